// Round 13
// baseline (744.372 us; speedup 1.0000x reference)
//
#include <hip/hip_runtime.h>
#include <hip/hip_bf16.h>
#include <math.h>
#include <stdint.h>

// CoAtNet transformer block, MI355X. R17 = R16 resubmit (prior bench died in
// infra, audit found no kernel fault; precedent R5->R6 flake). B-operand
// direct from global/L2 into registers (bf16x8 fragments), LDS holds only
// the A double-buffer (16KB). R15 counters showed the GEMM is LDS-BW-bound
// (72KB/block-step x 3 blocks ~= K-step window at 85B/cy). Everything else
// unchanged from R15 (ln_coal, attn_mfma, precision, host dtype dispatch).

typedef __bf16 bf16;
typedef __attribute__((ext_vector_type(8))) __bf16 bf16x8;
typedef __attribute__((ext_vector_type(4))) __bf16 bf16x4;
typedef __attribute__((ext_vector_type(4))) float f32x4;

#define NN 784      // H*W tokens
#define CC 512      // channels
#define NHEADS 16
#define DHEAD 32
#define FFD 2048
#define NBATCH 16
#define NREL 1596
#define MFULL (NBATCH * NN)   // 12544 = 98 * 128
#define PACKSZ ((size_t)6422528)  // elements per qkv-pack region

// ---------------------------------------------------------------------------
// Dtype detector (fallback only): flag=1 -> bf16, flag=0 -> fp32.
// ---------------------------------------------------------------------------
__global__ __launch_bounds__(256) void detect_dtype(const unsigned int* xw, int* flag)
{
  __shared__ int cnt[256];
  int plausible = 0;
  for (int i = threadIdx.x; i < 1024; i += 256) {
    unsigned w = xw[i];
    unsigned lo = w & 0xFFFFu;
    unsigned e = (lo >> 7) & 0xFFu;
    if (lo == 0u || (e >= 90u && e <= 140u)) plausible++;
  }
  cnt[threadIdx.x] = plausible;
  __syncthreads();
  if (threadIdx.x == 0) {
    int tot = 0;
    for (int i = 0; i < 256; i++) tot += cnt[i];
    flag[0] = (tot >= 768) ? 1 : 0;
  }
}

__global__ void set_flag(int* flag, int v) { flag[0] = v; }

// ===========================================================================
// FP32 fast path (flag == 0)
// ===========================================================================

// All six weight transposes in ONE kernel.
__global__ __launch_bounds__(256) void transpose_split_all(
    const float* __restrict__ Wq, const float* __restrict__ Wk,
    const float* __restrict__ Wv, const float* __restrict__ Wo,
    const float* __restrict__ W1, const float* __restrict__ W2,
    bf16* __restrict__ WqkvT_h, bf16* __restrict__ WqkvT_l,
    bf16* __restrict__ WoT_h,   bf16* __restrict__ WoT_l,
    bf16* __restrict__ W1T_h,   bf16* __restrict__ W1T_l,
    bf16* __restrict__ W2T_h,   bf16* __restrict__ W2T_l,
    const int* __restrict__ flag)
{
  if (flag[0] != 0) return;
  int id = blockIdx.x;
  const float* W; bf16 *th, *tl; int K, Nout, roff, nx;
  if (id < 256)       { W = Wq; th = WqkvT_h; tl = WqkvT_l; K = 512;  Nout = 512;  roff = 0;    nx = 16; }
  else if (id < 512)  { W = Wk; th = WqkvT_h; tl = WqkvT_l; K = 512;  Nout = 512;  roff = 512;  nx = 16; id -= 256; }
  else if (id < 768)  { W = Wv; th = WqkvT_h; tl = WqkvT_l; K = 512;  Nout = 512;  roff = 1024; nx = 16; id -= 512; }
  else if (id < 1024) { W = Wo; th = WoT_h;   tl = WoT_l;   K = 512;  Nout = 512;  roff = 0;    nx = 16; id -= 768; }
  else if (id < 2048) { W = W1; th = W1T_h;   tl = W1T_l;   K = 512;  Nout = 2048; roff = 0;    nx = 64; id -= 1024; }
  else                { W = W2; th = W2T_h;   tl = W2T_l;   K = 2048; Nout = 512;  roff = 0;    nx = 16; id -= 2048; }
  const int n0 = (id % nx) * 32, k0 = (id / nx) * 32;

  __shared__ float tile[32][33];
  int tx = threadIdx.x & 31, ty = threadIdx.x >> 5;   // 32 x 8
  #pragma unroll
  for (int r = 0; r < 32; r += 8)
    tile[ty + r][tx] = W[(size_t)(k0 + ty + r) * Nout + n0 + tx];
  __syncthreads();
  #pragma unroll
  for (int r = 0; r < 32; r += 8) {
    float v = tile[tx][ty + r];            // = W[k0+tx][n0+ty+r]
    bf16 h = (bf16)v;
    float lo = v - (float)h;
    size_t idx = (size_t)(roff + n0 + ty + r) * K + k0 + tx;
    th[idx] = h;
    tl[idx] = (bf16)lo;
  }
}

// Coalesced LayerNorm: x (b,C,N) fp32 -> xn single bf16 (M,C).
__global__ __launch_bounds__(256) void ln_coal(
    const float* __restrict__ x, const float* __restrict__ lnw,
    const float* __restrict__ lnb, bf16* __restrict__ xh,
    const int* __restrict__ flag)
{
  if (flag[0] != 0) return;
  const int b = blockIdx.y;
  const int n0 = blockIdx.x * 64;
  const int w = threadIdx.x >> 6, l = threadIdx.x & 63;
  const bool act = (n0 + l) < NN;
  int tok = n0 + l; if (tok >= NN) tok = NN - 1;
  const float* xb = x + ((size_t)b * CC + w * 128) * NN + tok;
  float vals[128];
  float s = 0.f, ss = 0.f;
  #pragma unroll
  for (int c = 0; c < 128; c++) {
    float v = xb[(size_t)c * NN];
    vals[c] = v; s += v; ss += v * v;
  }
  __shared__ float S[4][64], SS[4][64];
  S[w][l] = s; SS[w][l] = ss;
  __syncthreads();
  const float St  = S[0][l] + S[1][l] + S[2][l] + S[3][l];
  const float SSt = SS[0][l] + SS[1][l] + SS[2][l] + SS[3][l];
  const float mu  = St * (1.f / 512.f);
  const float var = SSt * (1.f / 512.f) - mu * mu;
  const float rstd = rsqrtf(var + 1e-5f);
  if (act) {
    const size_t row = ((size_t)b * NN + n0 + l) * CC + w * 128;
    #pragma unroll
    for (int cc = 0; cc < 16; cc++) {
      bf16x8 o;
      #pragma unroll
      for (int e = 0; e < 8; e++) {
        const int c = cc * 8 + e;
        o[e] = (bf16)((vals[c] - mu) * rstd * lnw[w * 128 + c] + lnb[w * 128 + c]);
      }
      *(bf16x8*)(xh + row + cc * 8) = o;
    }
  }
}

// ---------------------------------------------------------------------------
// 2-MFMA split GEMM, B-direct: 128x128 tile, 4 waves 2x2, dbuf 1-barrier
// K-loop (BK=32). A staged in LDS (16KB dbuf, global_load_lds); B hi/lo
// fragments loaded straight from global into registers each K-step (L1/L2
// served; fragments are 16 rows x 64B contiguous). C = A*Bh + A*Bl.
// 1D XCD chunk swizzle. ACT: 1 = exact gelu.
// RESM: 0 none; 1 += extra_f[(b,C,N)] fp32; 2 += ex_hi+ex_lo [(M,CC)] split.
// OUTM: 3 split hi/lo (M,NOUT); 4 fp32 (b,C,N); 6 single bf16 (M,NOUT);
//       5 QKV pack single: Q @0, K @PACKSZ, Vt [bh][32][784] @2*PACKSZ.
// ---------------------------------------------------------------------------
template <int NOUT, int KD, int ACT, int RESM, int OUTM>
__global__ __launch_bounds__(256) void gemm2(
    const bf16* __restrict__ A,
    const bf16* __restrict__ Bh, const bf16* __restrict__ Bl,
    const float* __restrict__ bias_q, const float* __restrict__ bias_k,
    const float* __restrict__ bias_v,
    float* __restrict__ outf, bf16* __restrict__ out_hi, bf16* __restrict__ out_lo,
    const float* __restrict__ extra_f, const bf16* __restrict__ ex_hi,
    const bf16* __restrict__ ex_lo,
    int M, const int* __restrict__ flag)
{
  if (flag[0] != 0) return;
  __shared__ bf16 sA[2][128 * 32];
  const int t = threadIdx.x;
  const int lane = t & 63;
  const int w = t >> 6;
  const int wr = w >> 1, wc = w & 1;
  const int lr = lane & 15, kg = lane >> 4;

  // 1D XCD-chunked bijective swizzle (all grids here have nwg % 8 == 0).
  int wg = blockIdx.y * gridDim.x + blockIdx.x;
  const int nwg = gridDim.x * gridDim.y;
  if ((nwg & 7) == 0) {
    const int cpx = nwg >> 3;
    wg = (wg & 7) * cpx + (wg >> 3);
  }
  const int tile_n = (wg % gridDim.x) * 128;
  const int tile_m = (wg / gridDim.x) * 128;

  f32x4 acc[4][4];
  #pragma unroll
  for (int m = 0; m < 4; m++)
    #pragma unroll
    for (int n = 0; n < 4; n++) acc[m][n] = (f32x4)0.f;

  // A staging: 512 x 16B segments per tile; thread t covers segs t and t+256.
  const int s0 = t, s1 = t + 256;
  int ar0 = tile_m + (s0 >> 2); if (ar0 >= M) ar0 = M - 1;
  int ar1 = tile_m + (s1 >> 2); if (ar1 >= M) ar1 = M - 1;
  const int ac0 = (s0 & 3) * 8, ac1 = (s1 & 3) * 8;
  const size_t a0 = (size_t)ar0 * KD + ac0;
  const size_t a1 = (size_t)ar1 * KD + ac1;

  // B fragment element offsets (shared by hi/lo): row * KD + kg*8.
  int boff[4];
  #pragma unroll
  for (int n = 0; n < 4; n++)
    boff[n] = (tile_n + wc * 64 + n * 16 + lr) * KD + kg * 8;

  #define STAGE_A(BUF, KO)                                                    \
    do {                                                                      \
      __builtin_amdgcn_global_load_lds(                                       \
          (const __attribute__((address_space(1))) void*)(A + a0 + (KO)),     \
          (__attribute__((address_space(3))) void*)(sA[BUF] + s0 * 8), 16, 0, 0); \
      __builtin_amdgcn_global_load_lds(                                       \
          (const __attribute__((address_space(1))) void*)(A + a1 + (KO)),     \
          (__attribute__((address_space(3))) void*)(sA[BUF] + s1 * 8), 16, 0, 0); \
    } while (0)

  // Prologue: stage first A tile, drain, barrier.
  STAGE_A(0, 0);
  asm volatile("s_waitcnt vmcnt(0)" ::: "memory");
  __builtin_amdgcn_sched_barrier(0);
  __builtin_amdgcn_s_barrier();
  __builtin_amdgcn_sched_barrier(0);

  int cur = 0;
  for (int k0 = 0; k0 < KD; k0 += 32) {
    if (k0 + 32 < KD) {
      if (cur) STAGE_A(0, k0 + 32); else STAGE_A(1, k0 + 32);
    }
    // B fragments for THIS step, direct from global (L1/L2).
    bf16x8 bh[4], bl[4];
    #pragma unroll
    for (int n = 0; n < 4; n++) {
      bh[n] = *(const bf16x8*)(Bh + boff[n] + k0);
      bl[n] = *(const bf16x8*)(Bl + boff[n] + k0);
    }
    const bf16* pA = sA[cur];
    bf16x8 af[4];
    #pragma unroll
    for (int m = 0; m < 4; m++) {
      const int off = (wr * 64 + m * 16 + lr) * 32 + kg * 8;
      af[m] = *(const bf16x8*)(pA + off);
    }
    #pragma unroll
    for (int m = 0; m < 4; m++)
      #pragma unroll
      for (int n = 0; n < 4; n++) {
        acc[m][n] = __builtin_amdgcn_mfma_f32_16x16x32_bf16(af[m], bh[n], acc[m][n], 0, 0, 0);
        acc[m][n] = __builtin_amdgcn_mfma_f32_16x16x32_bf16(af[m], bl[n], acc[m][n], 0, 0, 0);
      }
    asm volatile("s_waitcnt vmcnt(0)" ::: "memory");
    __builtin_amdgcn_sched_barrier(0);
    __builtin_amdgcn_s_barrier();
    __builtin_amdgcn_sched_barrier(0);
    cur ^= 1;
  }
  #undef STAGE_A

  // Epilogue. C/D layout: col = lane&15, row = 4*(lane>>4) + reg.
  #pragma unroll
  for (int m = 0; m < 4; m++) {
    const int r0 = tile_m + wr * 64 + m * 16 + kg * 4;
    #pragma unroll
    for (int n = 0; n < 4; n++) {
      const int cg = tile_n + wc * 64 + n * 16 + lr;
      float bv;
      if (OUTM == 5) {
        const int reg2 = cg >> 9;
        const float* bp = reg2 == 0 ? bias_q : (reg2 == 1 ? bias_k : bias_v);
        bv = bp[cg & 511];
      } else {
        bv = bias_q[cg];
      }
      #pragma unroll
      for (int j = 0; j < 4; j++) {
        const int rg = r0 + j;
        if (rg >= M) continue;
        float vacc = acc[m][n][j] + bv;
        if (ACT == 1) vacc = 0.5f * vacc * (1.f + erff(vacc * 0.70710678118654752f));
        if (RESM == 1) {
          int bl_ = rg / NN, nn = rg - bl_ * NN;
          vacc += extra_f[((size_t)bl_ * CC + cg) * NN + nn];
        }
        if (RESM == 2) {
          size_t ei = (size_t)rg * CC + cg;
          vacc += (float)ex_hi[ei] + (float)ex_lo[ei];
        }
        if (OUTM == 3) {
          size_t oi = (size_t)rg * NOUT + cg;
          bf16 h = (bf16)vacc;
          out_hi[oi] = h;
          out_lo[oi] = (bf16)(vacc - (float)h);
        } else if (OUTM == 4) {
          int bl_ = rg / NN, nn = rg - bl_ * NN;
          outf[((size_t)bl_ * CC + cg) * NN + nn] = vacc;
        } else if (OUTM == 6) {
          out_hi[(size_t)rg * NOUT + cg] = (bf16)vacc;
        } else if (OUTM == 5) {
          const int reg2 = cg >> 9;
          const int c = cg & 511;
          const int hh = c >> 5, dd = c & 31;
          const int bl_ = rg / NN, nn = rg - bl_ * NN;
          const int bh_ = bl_ * NHEADS + hh;
          bf16 h = (bf16)vacc;
          if (reg2 == 0) {
            out_hi[((size_t)bh_ * NN + nn) * 32 + dd] = h;
          } else if (reg2 == 1) {
            out_hi[PACKSZ + ((size_t)bh_ * NN + nn) * 32 + dd] = h;
          } else {
            out_hi[2 * PACKSZ + ((size_t)bh_ * 32 + dd) * NN + nn] = h;
          }
        }
      }
    }
  }
}

// ---------------------------------------------------------------------------
// MFMA flash attention (unchanged). Grid (13, H, B), 4 waves/block.
// ---------------------------------------------------------------------------
__global__ __launch_bounds__(256) void attn_mfma(
    const bf16* __restrict__ pack, const float* __restrict__ relb,
    bf16* __restrict__ o_out, const int* __restrict__ flag)
{
  if (flag[0] != 0) return;
  const int h = blockIdx.y, b = blockIdx.z;
  __shared__ float biasLds[NREL];
  for (int i = threadIdx.x; i < NREL; i += 256) biasLds[i] = relb[(size_t)h * NREL + i];
  __syncthreads();
  const int w = threadIdx.x >> 6, lane = threadIdx.x & 63;
  const int qtile = blockIdx.x * 4 + w;
  if (qtile >= 49) return;
  const int kg = lane >> 4, lq = lane & 15;
  const int qg = qtile * 16 + lq;
  const int bh = b * NHEADS + h;
  const bf16* Q  = pack;
  const bf16* K  = pack + PACKSZ;
  const bf16* Vt = pack + 2 * PACKSZ;
  __shared__ bf16 Plds[4][16][72];

  const bf16x8 qf = *(const bf16x8*)(Q + ((size_t)bh * NN + qg) * 32 + kg * 8);

  float m = -1e30f, l = 0.f;
  f32x4 o0 = (f32x4)0.f, o1 = (f32x4)0.f;
  const float* bb = biasLds + 812 - qg;   // bb[kv] = bias(kv, q=qg)
  const size_t vrow0 = ((size_t)bh * 32 + lq) * NN;
  const size_t vrow1 = ((size_t)bh * 32 + 16 + lq) * NN;

  for (int c = 0; c < 12; c++) {
    const int c0 = c * 64;
    f32x4 st[4];
    #pragma unroll
    for (int t = 0; t < 4; t++) {
      const int kvr = c0 + t * 16 + lq;
      const bf16x8 kf = *(const bf16x8*)(K + ((size_t)bh * NN + kvr) * 32 + kg * 8);
      st[t] = __builtin_amdgcn_mfma_f32_16x16x32_bf16(kf, qf, (f32x4)0.f, 0, 0, 0);
    }
    float cm = -1e30f;
    #pragma unroll
    for (int t = 0; t < 4; t++)
      #pragma unroll
      for (int r = 0; r < 4; r++) {
        st[t][r] += bb[c0 + t * 16 + 4 * kg + r];
        cm = fmaxf(cm, st[t][r]);
      }
    cm = fmaxf(cm, __shfl_xor(cm, 16));
    cm = fmaxf(cm, __shfl_xor(cm, 32));
    const float mn = fmaxf(m, cm);
    const float al = __expf(m - mn);
    m = mn;
    float cl = 0.f;
    #pragma unroll
    for (int t = 0; t < 4; t++) {
      bf16x4 pk;
      #pragma unroll
      for (int r = 0; r < 4; r++) {
        float p = __expf(st[t][r] - m);
        bf16 pb = (bf16)p;
        pk[r] = pb;
        cl += (float)pb;
      }
      *(bf16x4*)(&Plds[w][lq][t * 16 + 4 * kg]) = pk;
    }
    cl += __shfl_xor(cl, 16);
    cl += __shfl_xor(cl, 32);
    l = l * al + cl;
    #pragma unroll
    for (int r = 0; r < 4; r++) {
      const float ar = __shfl(al, (lane & 48) | (kg * 4 + r));
      o0[r] *= ar; o1[r] *= ar;
    }
    #pragma unroll
    for (int s2 = 0; s2 < 2; s2++) {
      const bf16x8 pa = *(const bf16x8*)(&Plds[w][lq][s2 * 32 + kg * 8]);
      const bf16x8 v0 = *(const bf16x8*)(Vt + vrow0 + c0 + s2 * 32 + kg * 8);
      const bf16x8 v1 = *(const bf16x8*)(Vt + vrow1 + c0 + s2 * 32 + kg * 8);
      o0 = __builtin_amdgcn_mfma_f32_16x16x32_bf16(pa, v0, o0, 0, 0, 0);
      o1 = __builtin_amdgcn_mfma_f32_16x16x32_bf16(pa, v1, o1, 0, 0, 0);
    }
  }

  // Tail: kv 768..783.
  {
    const int c0 = 768;
    const int kvr = c0 + lq;
    const bf16x8 kf = *(const bf16x8*)(K + ((size_t)bh * NN + kvr) * 32 + kg * 8);
    f32x4 a = __builtin_amdgcn_mfma_f32_16x16x32_bf16(kf, qf, (f32x4)0.f, 0, 0, 0);
    float cm = -1e30f;
    #pragma unroll
    for (int r = 0; r < 4; r++) {
      a[r] += bb[c0 + 4 * kg + r];
      cm = fmaxf(cm, a[r]);
    }
    cm = fmaxf(cm, __shfl_xor(cm, 16));
    cm = fmaxf(cm, __shfl_xor(cm, 32));
    const float mn = fmaxf(m, cm);
    const float al = __expf(m - mn);
    m = mn;
    float cl = 0.f;
    bf16x4 pk, zk;
    #pragma unroll
    for (int r = 0; r < 4; r++) {
      float p = __expf(a[r] - m);
      bf16 pb = (bf16)p;
      pk[r] = pb;
      zk[r] = (bf16)0.f;
      cl += (float)pb;
    }
    *(bf16x4*)(&Plds[w][lq][4 * kg]) = pk;
    *(bf16x4*)(&Plds[w][lq][16 + 4 * kg]) = zk;   // zero-pad k 16..31
    cl += __shfl_xor(cl, 16);
    cl += __shfl_xor(cl, 32);
    l = l * al + cl;
    #pragma unroll
    for (int r = 0; r < 4; r++) {
      const float ar = __shfl(al, (lane & 48) | (kg * 4 + r));
      o0[r] *= ar; o1[r] *= ar;
    }
    bf16x8 vz;
    #pragma unroll
    for (int e = 0; e < 8; e++) vz[e] = (bf16)0.f;
    const int voff = c0 + (kg < 2 ? kg * 8 : 0);
    bf16x8 v0 = *(const bf16x8*)(Vt + vrow0 + voff);
    bf16x8 v1 = *(const bf16x8*)(Vt + vrow1 + voff);
    if (kg >= 2) { v0 = vz; v1 = vz; }
    const bf16x8 pa = *(const bf16x8*)(&Plds[w][lq][kg * 8]);
    o0 = __builtin_amdgcn_mfma_f32_16x16x32_bf16(pa, v0, o0, 0, 0, 0);
    o1 = __builtin_amdgcn_mfma_f32_16x16x32_bf16(pa, v1, o1, 0, 0, 0);
  }

  const float inv = 1.f / l;
  #pragma unroll
  for (int r = 0; r < 4; r++) {
    const float ir = __shfl(inv, (lane & 48) | (kg * 4 + r));
    const int rq = qtile * 16 + kg * 4 + r;
    const size_t oi = ((size_t)b * NN + rq) * CC + h * DHEAD;
    o_out[oi + lq]      = (bf16)(o0[r] * ir);
    o_out[oi + 16 + lq] = (bf16)(o1[r] * ir);
  }
}

// ---------------------------------------------------------------------------
// fp32 fast pipeline (full batch)
// ---------------------------------------------------------------------------
static void run_fast_fp32(void* const* d_in, void* d_out, char* base,
                          const int* flag, hipStream_t stream)
{
  const float* x    = (const float*)d_in[0];
  const float* lnw  = (const float*)d_in[1];
  const float* lnb  = (const float*)d_in[2];
  const float* Wq   = (const float*)d_in[3];
  const float* bq   = (const float*)d_in[4];
  const float* Wk   = (const float*)d_in[5];
  const float* bk   = (const float*)d_in[6];
  const float* Wv   = (const float*)d_in[7];
  const float* bv   = (const float*)d_in[8];
  const float* Wo   = (const float*)d_in[9];
  const float* bo   = (const float*)d_in[10];
  const float* relb = (const float*)d_in[11];
  const float* W1   = (const float*)d_in[12];
  const float* b1   = (const float*)d_in[13];
  const float* W2   = (const float*)d_in[14];
  const float* b2   = (const float*)d_in[15];
  float* outp = (float*)d_out;

  bf16* WqkvT_h = (bf16*)(base);
  bf16* WqkvT_l = WqkvT_h + (size_t)1536 * 512;
  bf16* WoT_h   = WqkvT_l + (size_t)1536 * 512;
  bf16* WoT_l   = WoT_h   + (size_t)512 * 512;
  bf16* W1T_h   = WoT_l   + (size_t)512 * 512;
  bf16* W1T_l   = W1T_h   + (size_t)2048 * 512;
  bf16* W2T_h   = W1T_l   + (size_t)2048 * 512;
  bf16* W2T_l   = W2T_h   + (size_t)512 * 2048;
  bf16* xn   = (bf16*)(base + 12582912);
  bf16* qkvp = (bf16*)(base + 25427968);
  bf16* x1_h = (bf16*)(base + 25427968);
  bf16* x1_l = (bf16*)(base + 38273024);
  bf16* ff   = (bf16*)(base + 51118080);
  bf16* at   = xn;   // xn dead after QKV

  transpose_split_all<<<dim3(3072), 256, 0, stream>>>(
      Wq, Wk, Wv, Wo, W1, W2,
      WqkvT_h, WqkvT_l, WoT_h, WoT_l, W1T_h, W1T_l, W2T_h, W2T_l, flag);

  const int M = MFULL;            // 12544 = 98 * 128
  const int gm = M / 128;         // 98

  ln_coal<<<dim3(13, NBATCH), 256, 0, stream>>>(x, lnw, lnb, xn, flag);

  // QKV fused -> single-bf16 attention pack.
  gemm2<1536, 512, 0, 0, 5><<<dim3(12, gm), 256, 0, stream>>>(
      xn, WqkvT_h, WqkvT_l, bq, bk, bv,
      (float*)nullptr, qkvp, (bf16*)nullptr,
      (const float*)nullptr, (const bf16*)nullptr, (const bf16*)nullptr,
      M, flag);

  attn_mfma<<<dim3(13, NHEADS, NBATCH), 256, 0, stream>>>(qkvp, relb, at, flag);

  // Wo: + residual x (b,C,N), out split x1 (x1 enters final output directly).
  gemm2<512, 512, 0, 1, 3><<<dim3(4, gm), 256, 0, stream>>>(
      at, WoT_h, WoT_l, bo, (const float*)nullptr, (const float*)nullptr,
      (float*)nullptr, x1_h, x1_l,
      x, (const bf16*)nullptr, (const bf16*)nullptr,
      M, flag);

  // FF1: gelu, out single bf16.
  gemm2<2048, 512, 1, 0, 6><<<dim3(16, gm), 256, 0, stream>>>(
      x1_h, W1T_h, W1T_l, b1, (const float*)nullptr, (const float*)nullptr,
      (float*)nullptr, ff, (bf16*)nullptr,
      (const float*)nullptr, (const bf16*)nullptr, (const bf16*)nullptr,
      M, flag);

  // FF2: + residual x1 (split), out fp32 (b,C,N) = d_out.
  gemm2<512, 2048, 0, 2, 4><<<dim3(4, gm), 256, 0, stream>>>(
      ff, W2T_h, W2T_l, b2, (const float*)nullptr, (const float*)nullptr,
      outp, (bf16*)nullptr, (bf16*)nullptr,
      (const float*)nullptr, x1_h, x1_l,
      M, flag);
}

// ===========================================================================
// Naive kernels (fallback paths)
// ===========================================================================
template <typename T, int WANT>
__global__ __launch_bounds__(256) void ln_naive(
    const T* __restrict__ x, const T* __restrict__ lnw, const T* __restrict__ lnb,
    T* __restrict__ xn, const int* __restrict__ flag)
{
  if (flag[0] != WANT) return;
  int bn = blockIdx.x;
  int b = bn / NN, n = bn - b * NN;
  const T* xb = x + (size_t)b * CC * NN + n;
  int t = threadIdx.x;
  float v0 = (float)xb[(size_t)t * NN];
  float v1 = (float)xb[(size_t)(t + 256) * NN];
  float s = v0 + v1, ss = v0 * v0 + v1 * v1;
  #pragma unroll
  for (int m = 32; m >= 1; m >>= 1) {
    s  += __shfl_xor(s,  m);
    ss += __shfl_xor(ss, m);
  }
  __shared__ float red[2][4];
  int w = t >> 6, l = t & 63;
  if (l == 0) { red[0][w] = s; red[1][w] = ss; }
  __syncthreads();
  float S  = red[0][0] + red[0][1] + red[0][2] + red[0][3];
  float SS = red[1][0] + red[1][1] + red[1][2] + red[1][3];
  float mu  = S * (1.f / 512.f);
  float var = SS * (1.f / 512.f) - mu * mu;
  float rstd = rsqrtf(var + 1e-5f);
  T* o = xn + (size_t)bn * CC;
  o[t]       = (T)(((v0 - mu) * rstd) * (float)lnw[t]       + (float)lnb[t]);
  o[t + 256] = (T)(((v1 - mu) * rstd) * (float)lnw[t + 256] + (float)lnb[t + 256]);
}

template <typename T, int NOUT, int KD, int ACT, int RESM, int OUTM, int WANT>
__global__ __launch_bounds__(256) void gemm_naive(
    const T* __restrict__ A, const T* __restrict__ W, const T* __restrict__ bias,
    T* __restrict__ out, const T* __restrict__ extra, const int* __restrict__ flag)
{
  if (flag[0] != WANT) return;
  __shared__ float a_t[16][17];
  __shared__ float w_t[16][17];
  int tx = threadIdx.x & 15, ty = threadIdx.x >> 4;
  int m0 = blockIdx.y * 16, bz = blockIdx.z;
  int mg = m0 + ty;
  int jg = blockIdx.x * 16 + tx;
  int ar = mg < NN ? mg : NN - 1;
  const T* Ab = A + (size_t)bz * NN * KD;
  float acc = 0.f;
  for (int k0 = 0; k0 < KD; k0 += 16) {
    a_t[ty][tx] = (float)Ab[(size_t)ar * KD + k0 + tx];
    w_t[ty][tx] = (float)W[(size_t)(k0 + ty) * NOUT + jg];
    __syncthreads();
    #pragma unroll
    for (int kk = 0; kk < 16; kk++)
      acc += a_t[ty][kk] * w_t[kk][tx];
    __syncthreads();
  }
  if (mg >= NN) return;
  acc += (float)bias[jg];
  if (ACT == 1) acc = 0.5f * acc * (1.f + erff(acc * 0.70710678118654752f));
  if (RESM == 1) acc += (float)extra[((size_t)bz * CC + jg) * NN + mg];
  if (RESM == 2) acc += (float)extra[((size_t)bz * NN + mg) * CC + jg];
  if (OUTM == 0) out[((size_t)bz * NN + mg) * NOUT + jg] = (T)acc;
  else           out[((size_t)bz * NOUT + jg) * NN + mg] = (T)acc;
}

template <typename T, int WANT>
__global__ __launch_bounds__(256) void attn_naive(
    const T* __restrict__ q, const T* __restrict__ k, const T* __restrict__ v,
    const T* __restrict__ rel_bias, const int* __restrict__ rel_idx,
    T* __restrict__ attn_out, const int* __restrict__ flag)
{
  if (flag[0] != WANT) return;
  int i = blockIdx.x * 256 + threadIdx.x;
  int h = blockIdx.y, b = blockIdx.z;
  if (i >= NN) return;
  const T* qr = q + ((size_t)b * NN + i) * CC + h * DHEAD;
  float qv[DHEAD];
  #pragma unroll
  for (int d = 0; d < DHEAD; d++) qv[d] = (float)qr[d];
  const int* ridx = rel_idx + (size_t)i * NN;
  const T* rb = rel_bias + (size_t)h * NREL;
  const T* kb = k + (size_t)b * NN * CC + h * DHEAD;
  const T* vb = v + (size_t)b * NN * CC + h * DHEAD;

  float m = -1e30f;
  for (int j = 0; j < NN; j++) {
    const T* kr = kb + (size_t)j * CC;
    float s = 0.f;
    #pragma unroll
    for (int d = 0; d < DHEAD; d++) s += qv[d] * (float)kr[d];
    s += (float)rb[ridx[j]];
    m = fmaxf(m, s);
  }
  float l = 0.f;
  float o[DHEAD];
  #pragma unroll
  for (int d = 0; d < DHEAD; d++) o[d] = 0.f;
  for (int j = 0; j < NN; j++) {
    const T* kr = kb + (size_t)j * CC;
    float s = 0.f;
    #pragma unroll
    for (int d = 0; d < DHEAD; d++) s += qv[d] * (float)kr[d];
    s += (float)rb[ridx[j]];
    float p = __expf(s - m);
    l += p;
    const T* vr = vb + (size_t)j * CC;
    #pragma unroll
    for (int d = 0; d < DHEAD; d++) o[d] += p * (float)vr[d];
  }
  float inv = 1.f / l;
  T* op = attn_out + ((size_t)b * NN + i) * CC + h * DHEAD;
  #pragma unroll
  for (int d = 0; d < DHEAD; d++) op[d] = (T)(o[d] * inv);
}

template <typename T, int WANT>
static void run_pipeline(void* const* d_in, void* d_out, char* buf, int Bc,
                         const int* flag, hipStream_t stream)
{
  const T* x    = (const T*)d_in[0];
  const T* lnw  = (const T*)d_in[1];
  const T* lnb  = (const T*)d_in[2];
  const T* Wq   = (const T*)d_in[3];
  const T* bq   = (const T*)d_in[4];
  const T* Wk   = (const T*)d_in[5];
  const T* bk   = (const T*)d_in[6];
  const T* Wv   = (const T*)d_in[7];
  const T* bv   = (const T*)d_in[8];
  const T* Wo   = (const T*)d_in[9];
  const T* bo   = (const T*)d_in[10];
  const T* relb = (const T*)d_in[11];
  const T* W1   = (const T*)d_in[12];
  const T* b1   = (const T*)d_in[13];
  const T* W2   = (const T*)d_in[14];
  const T* b2   = (const T*)d_in[15];
  const int* reli = (const int*)d_in[16];
  T* outp = (T*)d_out;

  const size_t TOK = (size_t)NN * CC;
  T* xn  = (T*)(buf);
  T* qb  = (T*)(buf + (size_t)Bc * TOK * 4);
  T* kb  = (T*)(buf + 2 * (size_t)Bc * TOK * 4);
  T* vb  = (T*)(buf + 3 * (size_t)Bc * TOK * 4);
  T* ff1 = (T*)(buf + 4 * (size_t)Bc * TOK * 4);
  T* attn_out = xn;
  T* x1 = qb;

  for (int c0 = 0; c0 < NBATCH; c0 += Bc) {
    const T* xc   = x    + (size_t)c0 * CC * NN;
    T*       outc = outp + (size_t)c0 * CC * NN;
    ln_naive<T, WANT><<<dim3(Bc * NN), 256, 0, stream>>>(xc, lnw, lnb, xn, flag);
    gemm_naive<T, CC, CC, 0, 0, 0, WANT><<<dim3(32, 49, Bc), 256, 0, stream>>>(xn, Wq, bq, qb, (const T*)nullptr, flag);
    gemm_naive<T, CC, CC, 0, 0, 0, WANT><<<dim3(32, 49, Bc), 256, 0, stream>>>(xn, Wk, bk, kb, (const T*)nullptr, flag);
    gemm_naive<T, CC, CC, 0, 0, 0, WANT><<<dim3(32, 49, Bc), 256, 0, stream>>>(xn, Wv, bv, vb, (const T*)nullptr, flag);
    attn_naive<T, WANT><<<dim3(4, NHEADS, Bc), 256, 0, stream>>>(qb, kb, vb, relb, reli, attn_out, flag);
    gemm_naive<T, CC, CC, 0, 1, 0, WANT><<<dim3(32, 49, Bc), 256, 0, stream>>>(attn_out, Wo, bo, x1, xc, flag);
    gemm_naive<T, FFD, CC, 1, 0, 0, WANT><<<dim3(128, 49, Bc), 256, 0, stream>>>(x1, W1, b1, ff1, (const T*)nullptr, flag);
    gemm_naive<T, CC, FFD, 0, 2, 1, WANT><<<dim3(32, 49, Bc), 256, 0, stream>>>(ff1, W2, b2, outc, x1, flag);
  }
}

extern "C" void kernel_launch(void* const* d_in, const int* in_sizes, int n_in,
                              void* d_out, int out_size, void* d_ws, size_t ws_size,
                              hipStream_t stream)
{
  int* flag = (int*)d_ws;
  char* base = (char*)d_ws + 256;
  size_t avail = ws_size > 256 ? ws_size - 256 : 0;

  const size_t REQ_FAST = 102498304;   // fast fp32 path total footprint
  const size_t PB16 = (size_t)(4 * NN * CC + NN * FFD) * 2;  // 6,422,528
  const size_t PB32 = (size_t)(4 * NN * CC + NN * FFD) * 4;  // 12,845,056

  // Host-side dtype resolution by exact byte size of x (16x512x28x28):
  // fp32 = 25,690,112 B; bf16 = 12,845,056 B. Anything else -> device detector.
  int dt = -1;
  if (n_in > 0) {
    if (in_sizes[0] == 25690112) dt = 0;
    else if (in_sizes[0] == 12845056) dt = 1;
  }

  if (dt == 0) {
    set_flag<<<dim3(1), 1, 0, stream>>>(flag, 0);
    if (avail >= REQ_FAST) {
      run_fast_fp32(d_in, d_out, base, flag, stream);
    } else {
      int Bc32 = 1;
      for (int c : {16, 8, 4, 2}) {
        if ((size_t)c * PB32 <= avail) { Bc32 = c; break; }
      }
      run_pipeline<float, 0>(d_in, d_out, base, Bc32, flag, stream);
    }
    return;
  }
  if (dt == 1) {
    set_flag<<<dim3(1), 1, 0, stream>>>(flag, 1);
    int Bc16 = 1;
    for (int c : {16, 8, 4, 2}) {
      if ((size_t)c * PB16 <= avail) { Bc16 = c; break; }
    }
    run_pipeline<bf16, 1>(d_in, d_out, base, Bc16, flag, stream);
    return;
  }

  // Ambiguous size: old behavior (device detector + both flag-gated paths).
  detect_dtype<<<dim3(1), 256, 0, stream>>>((const unsigned int*)d_in[0], flag);
  if (avail >= REQ_FAST) {
    run_fast_fp32(d_in, d_out, base, flag, stream);
  } else {
    int Bc32 = 1;
    for (int c : {16, 8, 4, 2}) {
      if ((size_t)c * PB32 <= avail) { Bc32 = c; break; }
    }
    run_pipeline<float, 0>(d_in, d_out, base, Bc32, flag, stream);
  }
  int Bc16 = 1;
  for (int c : {16, 8, 4, 2}) {
    if ((size_t)c * PB16 <= avail) { Bc16 = c; break; }
  }
  run_pipeline<bf16, 1>(d_in, d_out, base, Bc16, flag, stream);
}

// Round 14
// 552.674 us; speedup vs baseline: 1.3469x; 1.3469x over previous
//
#include <hip/hip_runtime.h>
#include <hip/hip_bf16.h>
#include <math.h>
#include <stdint.h>

// CoAtNet transformer block, MI355X. R18: revert to R15 base (best, 561us) +
// BN template param on gemm2; Wo and FF2 (NOUT=512, grid-starved at 392
// blocks) use BN=64 -> 784 blocks, 32KB LDS, ~5 blocks/CU. QKV/FF1 keep
// BN=128. B-direct (R17) refuted: un-hidden global loads in drain-0 loop.

typedef __bf16 bf16;
typedef __attribute__((ext_vector_type(8))) __bf16 bf16x8;
typedef __attribute__((ext_vector_type(4))) __bf16 bf16x4;
typedef __attribute__((ext_vector_type(4))) float f32x4;

#define NN 784      // H*W tokens
#define CC 512      // channels
#define NHEADS 16
#define DHEAD 32
#define FFD 2048
#define NBATCH 16
#define NREL 1596
#define MFULL (NBATCH * NN)   // 12544 = 98 * 128
#define PACKSZ ((size_t)6422528)  // elements per qkv-pack region

// ---------------------------------------------------------------------------
// Dtype detector (fallback only): flag=1 -> bf16, flag=0 -> fp32.
// ---------------------------------------------------------------------------
__global__ __launch_bounds__(256) void detect_dtype(const unsigned int* xw, int* flag)
{
  __shared__ int cnt[256];
  int plausible = 0;
  for (int i = threadIdx.x; i < 1024; i += 256) {
    unsigned w = xw[i];
    unsigned lo = w & 0xFFFFu;
    unsigned e = (lo >> 7) & 0xFFu;
    if (lo == 0u || (e >= 90u && e <= 140u)) plausible++;
  }
  cnt[threadIdx.x] = plausible;
  __syncthreads();
  if (threadIdx.x == 0) {
    int tot = 0;
    for (int i = 0; i < 256; i++) tot += cnt[i];
    flag[0] = (tot >= 768) ? 1 : 0;
  }
}

__global__ void set_flag(int* flag, int v) { flag[0] = v; }

// ===========================================================================
// FP32 fast path (flag == 0)
// ===========================================================================

// All six weight transposes in ONE kernel.
__global__ __launch_bounds__(256) void transpose_split_all(
    const float* __restrict__ Wq, const float* __restrict__ Wk,
    const float* __restrict__ Wv, const float* __restrict__ Wo,
    const float* __restrict__ W1, const float* __restrict__ W2,
    bf16* __restrict__ WqkvT_h, bf16* __restrict__ WqkvT_l,
    bf16* __restrict__ WoT_h,   bf16* __restrict__ WoT_l,
    bf16* __restrict__ W1T_h,   bf16* __restrict__ W1T_l,
    bf16* __restrict__ W2T_h,   bf16* __restrict__ W2T_l,
    const int* __restrict__ flag)
{
  if (flag[0] != 0) return;
  int id = blockIdx.x;
  const float* W; bf16 *th, *tl; int K, Nout, roff, nx;
  if (id < 256)       { W = Wq; th = WqkvT_h; tl = WqkvT_l; K = 512;  Nout = 512;  roff = 0;    nx = 16; }
  else if (id < 512)  { W = Wk; th = WqkvT_h; tl = WqkvT_l; K = 512;  Nout = 512;  roff = 512;  nx = 16; id -= 256; }
  else if (id < 768)  { W = Wv; th = WqkvT_h; tl = WqkvT_l; K = 512;  Nout = 512;  roff = 1024; nx = 16; id -= 512; }
  else if (id < 1024) { W = Wo; th = WoT_h;   tl = WoT_l;   K = 512;  Nout = 512;  roff = 0;    nx = 16; id -= 768; }
  else if (id < 2048) { W = W1; th = W1T_h;   tl = W1T_l;   K = 512;  Nout = 2048; roff = 0;    nx = 64; id -= 1024; }
  else                { W = W2; th = W2T_h;   tl = W2T_l;   K = 2048; Nout = 512;  roff = 0;    nx = 16; id -= 2048; }
  const int n0 = (id % nx) * 32, k0 = (id / nx) * 32;

  __shared__ float tile[32][33];
  int tx = threadIdx.x & 31, ty = threadIdx.x >> 5;   // 32 x 8
  #pragma unroll
  for (int r = 0; r < 32; r += 8)
    tile[ty + r][tx] = W[(size_t)(k0 + ty + r) * Nout + n0 + tx];
  __syncthreads();
  #pragma unroll
  for (int r = 0; r < 32; r += 8) {
    float v = tile[tx][ty + r];            // = W[k0+tx][n0+ty+r]
    bf16 h = (bf16)v;
    float lo = v - (float)h;
    size_t idx = (size_t)(roff + n0 + ty + r) * K + k0 + tx;
    th[idx] = h;
    tl[idx] = (bf16)lo;
  }
}

// Coalesced LayerNorm: x (b,C,N) fp32 -> xn single bf16 (M,C).
__global__ __launch_bounds__(256) void ln_coal(
    const float* __restrict__ x, const float* __restrict__ lnw,
    const float* __restrict__ lnb, bf16* __restrict__ xh,
    const int* __restrict__ flag)
{
  if (flag[0] != 0) return;
  const int b = blockIdx.y;
  const int n0 = blockIdx.x * 64;
  const int w = threadIdx.x >> 6, l = threadIdx.x & 63;
  const bool act = (n0 + l) < NN;
  int tok = n0 + l; if (tok >= NN) tok = NN - 1;
  const float* xb = x + ((size_t)b * CC + w * 128) * NN + tok;
  float vals[128];
  float s = 0.f, ss = 0.f;
  #pragma unroll
  for (int c = 0; c < 128; c++) {
    float v = xb[(size_t)c * NN];
    vals[c] = v; s += v; ss += v * v;
  }
  __shared__ float S[4][64], SS[4][64];
  S[w][l] = s; SS[w][l] = ss;
  __syncthreads();
  const float St  = S[0][l] + S[1][l] + S[2][l] + S[3][l];
  const float SSt = SS[0][l] + SS[1][l] + SS[2][l] + SS[3][l];
  const float mu  = St * (1.f / 512.f);
  const float var = SSt * (1.f / 512.f) - mu * mu;
  const float rstd = rsqrtf(var + 1e-5f);
  if (act) {
    const size_t row = ((size_t)b * NN + n0 + l) * CC + w * 128;
    #pragma unroll
    for (int cc = 0; cc < 16; cc++) {
      bf16x8 o;
      #pragma unroll
      for (int e = 0; e < 8; e++) {
        const int c = cc * 8 + e;
        o[e] = (bf16)((vals[c] - mu) * rstd * lnw[w * 128 + c] + lnb[w * 128 + c]);
      }
      *(bf16x8*)(xh + row + cc * 8) = o;
    }
  }
}

// ---------------------------------------------------------------------------
// 2-MFMA split GEMM (R11/R15 structure, BN templated): 128xBN tile, 4 waves
// 2x2 (wave tile 64 x BN/2), dbuf 1-barrier K-loop (BK=32), LDS
// (16 + BN/4) KB. C = A*Bh + A*Bl. 1D XCD chunk swizzle.
// ACT: 1 = exact gelu.
// RESM: 0 none; 1 += extra_f[(b,C,N)] fp32; 2 += ex_hi+ex_lo [(M,CC)] split.
// OUTM: 3 split hi/lo (M,NOUT); 4 fp32 (b,C,N); 6 single bf16 (M,NOUT);
//       5 QKV pack single: Q @0, K @PACKSZ, Vt [bh][32][784] @2*PACKSZ.
// ---------------------------------------------------------------------------
template <int NOUT, int KD, int ACT, int RESM, int OUTM, int BN = 128>
__global__ __launch_bounds__(256) void gemm2(
    const bf16* __restrict__ A,
    const bf16* __restrict__ Bh, const bf16* __restrict__ Bl,
    const float* __restrict__ bias_q, const float* __restrict__ bias_k,
    const float* __restrict__ bias_v,
    float* __restrict__ outf, bf16* __restrict__ out_hi, bf16* __restrict__ out_lo,
    const float* __restrict__ extra_f, const bf16* __restrict__ ex_hi,
    const bf16* __restrict__ ex_lo,
    int M, const int* __restrict__ flag)
{
  if (flag[0] != 0) return;
  constexpr int NFR = BN / 32;      // B fragments per wave (n dir)
  constexpr int WN  = BN / 2;       // wave tile n-width
  constexpr int BSTG = BN / 64;     // B staging loads per thread per tile
  __shared__ bf16 sA [2][128 * 32];
  __shared__ bf16 sBh[2][BN * 32];
  __shared__ bf16 sBl[2][BN * 32];
  const int t = threadIdx.x;
  const int lane = t & 63;
  const int w = t >> 6;
  const int wr = w >> 1, wc = w & 1;
  const int lr = lane & 15, kg = lane >> 4;

  // 1D XCD-chunked bijective swizzle (all grids here have nwg % 8 == 0).
  int wg = blockIdx.y * gridDim.x + blockIdx.x;
  const int nwg = gridDim.x * gridDim.y;
  if ((nwg & 7) == 0) {
    const int cpx = nwg >> 3;
    wg = (wg & 7) * cpx + (wg >> 3);
  }
  const int tile_n = (wg % gridDim.x) * BN;
  const int tile_m = (wg / gridDim.x) * 128;

  f32x4 acc[4][NFR];
  #pragma unroll
  for (int m = 0; m < 4; m++)
    #pragma unroll
    for (int n = 0; n < NFR; n++) acc[m][n] = (f32x4)0.f;

  // A staging: 512 x 16B segs (2/thread). B staging: BN*4 segs (BSTG/thread).
  size_t aoff[2];
  #pragma unroll
  for (int i = 0; i < 2; i++) {
    const int seg = t + 256 * i;
    int r = tile_m + (seg >> 2); if (r >= M) r = M - 1;
    aoff[i] = (size_t)r * KD + (seg & 3) * 8;
  }
  size_t bsoff[BSTG > 0 ? BSTG : 1];
  #pragma unroll
  for (int i = 0; i < BSTG; i++) {
    const int seg = t + 256 * i;
    bsoff[i] = (size_t)(tile_n + (seg >> 2)) * KD + (seg & 3) * 8;
  }

  #define STAGE(BUF, KO)                                                        \
    do {                                                                        \
      _Pragma("unroll")                                                         \
      for (int i = 0; i < 2; i++)                                               \
        __builtin_amdgcn_global_load_lds(                                       \
            (const __attribute__((address_space(1))) void*)(A + aoff[i] + (KO)),\
            (__attribute__((address_space(3))) void*)(sA[BUF] + (t + 256 * i) * 8), 16, 0, 0); \
      _Pragma("unroll")                                                         \
      for (int i = 0; i < BSTG; i++) {                                          \
        __builtin_amdgcn_global_load_lds(                                       \
            (const __attribute__((address_space(1))) void*)(Bh + bsoff[i] + (KO)),\
            (__attribute__((address_space(3))) void*)(sBh[BUF] + (t + 256 * i) * 8), 16, 0, 0); \
        __builtin_amdgcn_global_load_lds(                                       \
            (const __attribute__((address_space(1))) void*)(Bl + bsoff[i] + (KO)),\
            (__attribute__((address_space(3))) void*)(sBl[BUF] + (t + 256 * i) * 8), 16, 0, 0); \
      }                                                                         \
    } while (0)

  // Prologue: stage first tile, drain, barrier.
  STAGE(0, 0);
  asm volatile("s_waitcnt vmcnt(0)" ::: "memory");
  __builtin_amdgcn_sched_barrier(0);
  __builtin_amdgcn_s_barrier();
  __builtin_amdgcn_sched_barrier(0);

  int cur = 0;
  for (int k0 = 0; k0 < KD; k0 += 32) {
    if (k0 + 32 < KD) {
      if (cur) STAGE(0, k0 + 32); else STAGE(1, k0 + 32);
    }
    const bf16* pA  = sA [cur];
    const bf16* pBh = sBh[cur];
    const bf16* pBl = sBl[cur];
    bf16x8 af[4], bhf[NFR], blf[NFR];
    #pragma unroll
    for (int m = 0; m < 4; m++) {
      const int off = (wr * 64 + m * 16 + lr) * 32 + kg * 8;
      af[m] = *(const bf16x8*)(pA + off);
    }
    #pragma unroll
    for (int n = 0; n < NFR; n++) {
      const int off = (wc * WN + n * 16 + lr) * 32 + kg * 8;
      bhf[n] = *(const bf16x8*)(pBh + off);
      blf[n] = *(const bf16x8*)(pBl + off);
    }
    #pragma unroll
    for (int m = 0; m < 4; m++)
      #pragma unroll
      for (int n = 0; n < NFR; n++) {
        acc[m][n] = __builtin_amdgcn_mfma_f32_16x16x32_bf16(af[m], bhf[n], acc[m][n], 0, 0, 0);
        acc[m][n] = __builtin_amdgcn_mfma_f32_16x16x32_bf16(af[m], blf[n], acc[m][n], 0, 0, 0);
      }
    asm volatile("s_waitcnt vmcnt(0)" ::: "memory");
    __builtin_amdgcn_sched_barrier(0);
    __builtin_amdgcn_s_barrier();
    __builtin_amdgcn_sched_barrier(0);
    cur ^= 1;
  }
  #undef STAGE

  // Epilogue. C/D layout: col = lane&15, row = 4*(lane>>4) + reg.
  #pragma unroll
  for (int m = 0; m < 4; m++) {
    const int r0 = tile_m + wr * 64 + m * 16 + kg * 4;
    #pragma unroll
    for (int n = 0; n < NFR; n++) {
      const int cg = tile_n + wc * WN + n * 16 + lr;
      float bv;
      if (OUTM == 5) {
        const int reg2 = cg >> 9;
        const float* bp = reg2 == 0 ? bias_q : (reg2 == 1 ? bias_k : bias_v);
        bv = bp[cg & 511];
      } else {
        bv = bias_q[cg];
      }
      #pragma unroll
      for (int j = 0; j < 4; j++) {
        const int rg = r0 + j;
        if (rg >= M) continue;
        float vacc = acc[m][n][j] + bv;
        if (ACT == 1) vacc = 0.5f * vacc * (1.f + erff(vacc * 0.70710678118654752f));
        if (RESM == 1) {
          int bl_ = rg / NN, nn = rg - bl_ * NN;
          vacc += extra_f[((size_t)bl_ * CC + cg) * NN + nn];
        }
        if (RESM == 2) {
          size_t ei = (size_t)rg * CC + cg;
          vacc += (float)ex_hi[ei] + (float)ex_lo[ei];
        }
        if (OUTM == 3) {
          size_t oi = (size_t)rg * NOUT + cg;
          bf16 h = (bf16)vacc;
          out_hi[oi] = h;
          out_lo[oi] = (bf16)(vacc - (float)h);
        } else if (OUTM == 4) {
          int bl_ = rg / NN, nn = rg - bl_ * NN;
          outf[((size_t)bl_ * CC + cg) * NN + nn] = vacc;
        } else if (OUTM == 6) {
          out_hi[(size_t)rg * NOUT + cg] = (bf16)vacc;
        } else if (OUTM == 5) {
          const int reg2 = cg >> 9;
          const int c = cg & 511;
          const int hh = c >> 5, dd = c & 31;
          const int bl_ = rg / NN, nn = rg - bl_ * NN;
          const int bh_ = bl_ * NHEADS + hh;
          bf16 h = (bf16)vacc;
          if (reg2 == 0) {
            out_hi[((size_t)bh_ * NN + nn) * 32 + dd] = h;
          } else if (reg2 == 1) {
            out_hi[PACKSZ + ((size_t)bh_ * NN + nn) * 32 + dd] = h;
          } else {
            out_hi[2 * PACKSZ + ((size_t)bh_ * 32 + dd) * NN + nn] = h;
          }
        }
      }
    }
  }
}

// ---------------------------------------------------------------------------
// MFMA flash attention (unchanged). Grid (13, H, B), 4 waves/block.
// ---------------------------------------------------------------------------
__global__ __launch_bounds__(256) void attn_mfma(
    const bf16* __restrict__ pack, const float* __restrict__ relb,
    bf16* __restrict__ o_out, const int* __restrict__ flag)
{
  if (flag[0] != 0) return;
  const int h = blockIdx.y, b = blockIdx.z;
  __shared__ float biasLds[NREL];
  for (int i = threadIdx.x; i < NREL; i += 256) biasLds[i] = relb[(size_t)h * NREL + i];
  __syncthreads();
  const int w = threadIdx.x >> 6, lane = threadIdx.x & 63;
  const int qtile = blockIdx.x * 4 + w;
  if (qtile >= 49) return;
  const int kg = lane >> 4, lq = lane & 15;
  const int qg = qtile * 16 + lq;
  const int bh = b * NHEADS + h;
  const bf16* Q  = pack;
  const bf16* K  = pack + PACKSZ;
  const bf16* Vt = pack + 2 * PACKSZ;
  __shared__ bf16 Plds[4][16][72];

  const bf16x8 qf = *(const bf16x8*)(Q + ((size_t)bh * NN + qg) * 32 + kg * 8);

  float m = -1e30f, l = 0.f;
  f32x4 o0 = (f32x4)0.f, o1 = (f32x4)0.f;
  const float* bb = biasLds + 812 - qg;   // bb[kv] = bias(kv, q=qg)
  const size_t vrow0 = ((size_t)bh * 32 + lq) * NN;
  const size_t vrow1 = ((size_t)bh * 32 + 16 + lq) * NN;

  for (int c = 0; c < 12; c++) {
    const int c0 = c * 64;
    f32x4 st[4];
    #pragma unroll
    for (int t = 0; t < 4; t++) {
      const int kvr = c0 + t * 16 + lq;
      const bf16x8 kf = *(const bf16x8*)(K + ((size_t)bh * NN + kvr) * 32 + kg * 8);
      st[t] = __builtin_amdgcn_mfma_f32_16x16x32_bf16(kf, qf, (f32x4)0.f, 0, 0, 0);
    }
    float cm = -1e30f;
    #pragma unroll
    for (int t = 0; t < 4; t++)
      #pragma unroll
      for (int r = 0; r < 4; r++) {
        st[t][r] += bb[c0 + t * 16 + 4 * kg + r];
        cm = fmaxf(cm, st[t][r]);
      }
    cm = fmaxf(cm, __shfl_xor(cm, 16));
    cm = fmaxf(cm, __shfl_xor(cm, 32));
    const float mn = fmaxf(m, cm);
    const float al = __expf(m - mn);
    m = mn;
    float cl = 0.f;
    #pragma unroll
    for (int t = 0; t < 4; t++) {
      bf16x4 pk;
      #pragma unroll
      for (int r = 0; r < 4; r++) {
        float p = __expf(st[t][r] - m);
        bf16 pb = (bf16)p;
        pk[r] = pb;
        cl += (float)pb;
      }
      *(bf16x4*)(&Plds[w][lq][t * 16 + 4 * kg]) = pk;
    }
    cl += __shfl_xor(cl, 16);
    cl += __shfl_xor(cl, 32);
    l = l * al + cl;
    #pragma unroll
    for (int r = 0; r < 4; r++) {
      const float ar = __shfl(al, (lane & 48) | (kg * 4 + r));
      o0[r] *= ar; o1[r] *= ar;
    }
    #pragma unroll
    for (int s2 = 0; s2 < 2; s2++) {
      const bf16x8 pa = *(const bf16x8*)(&Plds[w][lq][s2 * 32 + kg * 8]);
      const bf16x8 v0 = *(const bf16x8*)(Vt + vrow0 + c0 + s2 * 32 + kg * 8);
      const bf16x8 v1 = *(const bf16x8*)(Vt + vrow1 + c0 + s2 * 32 + kg * 8);
      o0 = __builtin_amdgcn_mfma_f32_16x16x32_bf16(pa, v0, o0, 0, 0, 0);
      o1 = __builtin_amdgcn_mfma_f32_16x16x32_bf16(pa, v1, o1, 0, 0, 0);
    }
  }

  // Tail: kv 768..783.
  {
    const int c0 = 768;
    const int kvr = c0 + lq;
    const bf16x8 kf = *(const bf16x8*)(K + ((size_t)bh * NN + kvr) * 32 + kg * 8);
    f32x4 a = __builtin_amdgcn_mfma_f32_16x16x32_bf16(kf, qf, (f32x4)0.f, 0, 0, 0);
    float cm = -1e30f;
    #pragma unroll
    for (int r = 0; r < 4; r++) {
      a[r] += bb[c0 + 4 * kg + r];
      cm = fmaxf(cm, a[r]);
    }
    cm = fmaxf(cm, __shfl_xor(cm, 16));
    cm = fmaxf(cm, __shfl_xor(cm, 32));
    const float mn = fmaxf(m, cm);
    const float al = __expf(m - mn);
    m = mn;
    float cl = 0.f;
    bf16x4 pk, zk;
    #pragma unroll
    for (int r = 0; r < 4; r++) {
      float p = __expf(a[r] - m);
      bf16 pb = (bf16)p;
      pk[r] = pb;
      zk[r] = (bf16)0.f;
      cl += (float)pb;
    }
    *(bf16x4*)(&Plds[w][lq][4 * kg]) = pk;
    *(bf16x4*)(&Plds[w][lq][16 + 4 * kg]) = zk;   // zero-pad k 16..31
    cl += __shfl_xor(cl, 16);
    cl += __shfl_xor(cl, 32);
    l = l * al + cl;
    #pragma unroll
    for (int r = 0; r < 4; r++) {
      const float ar = __shfl(al, (lane & 48) | (kg * 4 + r));
      o0[r] *= ar; o1[r] *= ar;
    }
    bf16x8 vz;
    #pragma unroll
    for (int e = 0; e < 8; e++) vz[e] = (bf16)0.f;
    const int voff = c0 + (kg < 2 ? kg * 8 : 0);
    bf16x8 v0 = *(const bf16x8*)(Vt + vrow0 + voff);
    bf16x8 v1 = *(const bf16x8*)(Vt + vrow1 + voff);
    if (kg >= 2) { v0 = vz; v1 = vz; }
    const bf16x8 pa = *(const bf16x8*)(&Plds[w][lq][kg * 8]);
    o0 = __builtin_amdgcn_mfma_f32_16x16x32_bf16(pa, v0, o0, 0, 0, 0);
    o1 = __builtin_amdgcn_mfma_f32_16x16x32_bf16(pa, v1, o1, 0, 0, 0);
  }

  const float inv = 1.f / l;
  #pragma unroll
  for (int r = 0; r < 4; r++) {
    const float ir = __shfl(inv, (lane & 48) | (kg * 4 + r));
    const int rq = qtile * 16 + kg * 4 + r;
    const size_t oi = ((size_t)b * NN + rq) * CC + h * DHEAD;
    o_out[oi + lq]      = (bf16)(o0[r] * ir);
    o_out[oi + 16 + lq] = (bf16)(o1[r] * ir);
  }
}

// ---------------------------------------------------------------------------
// fp32 fast pipeline (full batch)
// ---------------------------------------------------------------------------
static void run_fast_fp32(void* const* d_in, void* d_out, char* base,
                          const int* flag, hipStream_t stream)
{
  const float* x    = (const float*)d_in[0];
  const float* lnw  = (const float*)d_in[1];
  const float* lnb  = (const float*)d_in[2];
  const float* Wq   = (const float*)d_in[3];
  const float* bq   = (const float*)d_in[4];
  const float* Wk   = (const float*)d_in[5];
  const float* bk   = (const float*)d_in[6];
  const float* Wv   = (const float*)d_in[7];
  const float* bv   = (const float*)d_in[8];
  const float* Wo   = (const float*)d_in[9];
  const float* bo   = (const float*)d_in[10];
  const float* relb = (const float*)d_in[11];
  const float* W1   = (const float*)d_in[12];
  const float* b1   = (const float*)d_in[13];
  const float* W2   = (const float*)d_in[14];
  const float* b2   = (const float*)d_in[15];
  float* outp = (float*)d_out;

  bf16* WqkvT_h = (bf16*)(base);
  bf16* WqkvT_l = WqkvT_h + (size_t)1536 * 512;
  bf16* WoT_h   = WqkvT_l + (size_t)1536 * 512;
  bf16* WoT_l   = WoT_h   + (size_t)512 * 512;
  bf16* W1T_h   = WoT_l   + (size_t)512 * 512;
  bf16* W1T_l   = W1T_h   + (size_t)2048 * 512;
  bf16* W2T_h   = W1T_l   + (size_t)2048 * 512;
  bf16* W2T_l   = W2T_h   + (size_t)512 * 2048;
  bf16* xn   = (bf16*)(base + 12582912);
  bf16* qkvp = (bf16*)(base + 25427968);
  bf16* x1_h = (bf16*)(base + 25427968);
  bf16* x1_l = (bf16*)(base + 38273024);
  bf16* ff   = (bf16*)(base + 51118080);
  bf16* at   = xn;   // xn dead after QKV

  transpose_split_all<<<dim3(3072), 256, 0, stream>>>(
      Wq, Wk, Wv, Wo, W1, W2,
      WqkvT_h, WqkvT_l, WoT_h, WoT_l, W1T_h, W1T_l, W2T_h, W2T_l, flag);

  const int M = MFULL;            // 12544 = 98 * 128
  const int gm = M / 128;         // 98

  ln_coal<<<dim3(13, NBATCH), 256, 0, stream>>>(x, lnw, lnb, xn, flag);

  // QKV fused -> single-bf16 attention pack. (BN=128)
  gemm2<1536, 512, 0, 0, 5, 128><<<dim3(12, gm), 256, 0, stream>>>(
      xn, WqkvT_h, WqkvT_l, bq, bk, bv,
      (float*)nullptr, qkvp, (bf16*)nullptr,
      (const float*)nullptr, (const bf16*)nullptr, (const bf16*)nullptr,
      M, flag);

  attn_mfma<<<dim3(13, NHEADS, NBATCH), 256, 0, stream>>>(qkvp, relb, at, flag);

  // Wo: + residual x (b,C,N), out split x1. BN=64 -> 784 blocks, 32KB LDS.
  gemm2<512, 512, 0, 1, 3, 64><<<dim3(8, gm), 256, 0, stream>>>(
      at, WoT_h, WoT_l, bo, (const float*)nullptr, (const float*)nullptr,
      (float*)nullptr, x1_h, x1_l,
      x, (const bf16*)nullptr, (const bf16*)nullptr,
      M, flag);

  // FF1: gelu, out single bf16. (BN=128)
  gemm2<2048, 512, 1, 0, 6, 128><<<dim3(16, gm), 256, 0, stream>>>(
      x1_h, W1T_h, W1T_l, b1, (const float*)nullptr, (const float*)nullptr,
      (float*)nullptr, ff, (bf16*)nullptr,
      (const float*)nullptr, (const bf16*)nullptr, (const bf16*)nullptr,
      M, flag);

  // FF2: + residual x1 (split), out fp32 (b,C,N). BN=64 -> 784 blocks.
  gemm2<512, 2048, 0, 2, 4, 64><<<dim3(8, gm), 256, 0, stream>>>(
      ff, W2T_h, W2T_l, b2, (const float*)nullptr, (const float*)nullptr,
      outp, (bf16*)nullptr, (bf16*)nullptr,
      (const float*)nullptr, x1_h, x1_l,
      M, flag);
}

// ===========================================================================
// Naive kernels (fallback paths)
// ===========================================================================
template <typename T, int WANT>
__global__ __launch_bounds__(256) void ln_naive(
    const T* __restrict__ x, const T* __restrict__ lnw, const T* __restrict__ lnb,
    T* __restrict__ xn, const int* __restrict__ flag)
{
  if (flag[0] != WANT) return;
  int bn = blockIdx.x;
  int b = bn / NN, n = bn - b * NN;
  const T* xb = x + (size_t)b * CC * NN + n;
  int t = threadIdx.x;
  float v0 = (float)xb[(size_t)t * NN];
  float v1 = (float)xb[(size_t)(t + 256) * NN];
  float s = v0 + v1, ss = v0 * v0 + v1 * v1;
  #pragma unroll
  for (int m = 32; m >= 1; m >>= 1) {
    s  += __shfl_xor(s,  m);
    ss += __shfl_xor(ss, m);
  }
  __shared__ float red[2][4];
  int w = t >> 6, l = t & 63;
  if (l == 0) { red[0][w] = s; red[1][w] = ss; }
  __syncthreads();
  float S  = red[0][0] + red[0][1] + red[0][2] + red[0][3];
  float SS = red[1][0] + red[1][1] + red[1][2] + red[1][3];
  float mu  = S * (1.f / 512.f);
  float var = SS * (1.f / 512.f) - mu * mu;
  float rstd = rsqrtf(var + 1e-5f);
  T* o = xn + (size_t)bn * CC;
  o[t]       = (T)(((v0 - mu) * rstd) * (float)lnw[t]       + (float)lnb[t]);
  o[t + 256] = (T)(((v1 - mu) * rstd) * (float)lnw[t + 256] + (float)lnb[t + 256]);
}

template <typename T, int NOUT, int KD, int ACT, int RESM, int OUTM, int WANT>
__global__ __launch_bounds__(256) void gemm_naive(
    const T* __restrict__ A, const T* __restrict__ W, const T* __restrict__ bias,
    T* __restrict__ out, const T* __restrict__ extra, const int* __restrict__ flag)
{
  if (flag[0] != WANT) return;
  __shared__ float a_t[16][17];
  __shared__ float w_t[16][17];
  int tx = threadIdx.x & 15, ty = threadIdx.x >> 4;
  int m0 = blockIdx.y * 16, bz = blockIdx.z;
  int mg = m0 + ty;
  int jg = blockIdx.x * 16 + tx;
  int ar = mg < NN ? mg : NN - 1;
  const T* Ab = A + (size_t)bz * NN * KD;
  float acc = 0.f;
  for (int k0 = 0; k0 < KD; k0 += 16) {
    a_t[ty][tx] = (float)Ab[(size_t)ar * KD + k0 + tx];
    w_t[ty][tx] = (float)W[(size_t)(k0 + ty) * NOUT + jg];
    __syncthreads();
    #pragma unroll
    for (int kk = 0; kk < 16; kk++)
      acc += a_t[ty][kk] * w_t[kk][tx];
    __syncthreads();
  }
  if (mg >= NN) return;
  acc += (float)bias[jg];
  if (ACT == 1) acc = 0.5f * acc * (1.f + erff(acc * 0.70710678118654752f));
  if (RESM == 1) acc += (float)extra[((size_t)bz * CC + jg) * NN + mg];
  if (RESM == 2) acc += (float)extra[((size_t)bz * NN + mg) * CC + jg];
  if (OUTM == 0) out[((size_t)bz * NN + mg) * NOUT + jg] = (T)acc;
  else           out[((size_t)bz * NOUT + jg) * NN + mg] = (T)acc;
}

template <typename T, int WANT>
__global__ __launch_bounds__(256) void attn_naive(
    const T* __restrict__ q, const T* __restrict__ k, const T* __restrict__ v,
    const T* __restrict__ rel_bias, const int* __restrict__ rel_idx,
    T* __restrict__ attn_out, const int* __restrict__ flag)
{
  if (flag[0] != WANT) return;
  int i = blockIdx.x * 256 + threadIdx.x;
  int h = blockIdx.y, b = blockIdx.z;
  if (i >= NN) return;
  const T* qr = q + ((size_t)b * NN + i) * CC + h * DHEAD;
  float qv[DHEAD];
  #pragma unroll
  for (int d = 0; d < DHEAD; d++) qv[d] = (float)qr[d];
  const int* ridx = rel_idx + (size_t)i * NN;
  const T* rb = rel_bias + (size_t)h * NREL;
  const T* kb = k + (size_t)b * NN * CC + h * DHEAD;
  const T* vb = v + (size_t)b * NN * CC + h * DHEAD;

  float m = -1e30f;
  for (int j = 0; j < NN; j++) {
    const T* kr = kb + (size_t)j * CC;
    float s = 0.f;
    #pragma unroll
    for (int d = 0; d < DHEAD; d++) s += qv[d] * (float)kr[d];
    s += (float)rb[ridx[j]];
    m = fmaxf(m, s);
  }
  float l = 0.f;
  float o[DHEAD];
  #pragma unroll
  for (int d = 0; d < DHEAD; d++) o[d] = 0.f;
  for (int j = 0; j < NN; j++) {
    const T* kr = kb + (size_t)j * CC;
    float s = 0.f;
    #pragma unroll
    for (int d = 0; d < DHEAD; d++) s += qv[d] * (float)kr[d];
    s += (float)rb[ridx[j]];
    float p = __expf(s - m);
    l += p;
    const T* vr = vb + (size_t)j * CC;
    #pragma unroll
    for (int d = 0; d < DHEAD; d++) o[d] += p * (float)vr[d];
  }
  float inv = 1.f / l;
  T* op = attn_out + ((size_t)b * NN + i) * CC + h * DHEAD;
  #pragma unroll
  for (int d = 0; d < DHEAD; d++) op[d] = (T)(o[d] * inv);
}

template <typename T, int WANT>
static void run_pipeline(void* const* d_in, void* d_out, char* buf, int Bc,
                         const int* flag, hipStream_t stream)
{
  const T* x    = (const T*)d_in[0];
  const T* lnw  = (const T*)d_in[1];
  const T* lnb  = (const T*)d_in[2];
  const T* Wq   = (const T*)d_in[3];
  const T* bq   = (const T*)d_in[4];
  const T* Wk   = (const T*)d_in[5];
  const T* bk   = (const T*)d_in[6];
  const T* Wv   = (const T*)d_in[7];
  const T* bv   = (const T*)d_in[8];
  const T* Wo   = (const T*)d_in[9];
  const T* bo   = (const T*)d_in[10];
  const T* relb = (const T*)d_in[11];
  const T* W1   = (const T*)d_in[12];
  const T* b1   = (const T*)d_in[13];
  const T* W2   = (const T*)d_in[14];
  const T* b2   = (const T*)d_in[15];
  const int* reli = (const int*)d_in[16];
  T* outp = (T*)d_out;

  const size_t TOK = (size_t)NN * CC;
  T* xn  = (T*)(buf);
  T* qb  = (T*)(buf + (size_t)Bc * TOK * 4);
  T* kb  = (T*)(buf + 2 * (size_t)Bc * TOK * 4);
  T* vb  = (T*)(buf + 3 * (size_t)Bc * TOK * 4);
  T* ff1 = (T*)(buf + 4 * (size_t)Bc * TOK * 4);
  T* attn_out = xn;
  T* x1 = qb;

  for (int c0 = 0; c0 < NBATCH; c0 += Bc) {
    const T* xc   = x    + (size_t)c0 * CC * NN;
    T*       outc = outp + (size_t)c0 * CC * NN;
    ln_naive<T, WANT><<<dim3(Bc * NN), 256, 0, stream>>>(xc, lnw, lnb, xn, flag);
    gemm_naive<T, CC, CC, 0, 0, 0, WANT><<<dim3(32, 49, Bc), 256, 0, stream>>>(xn, Wq, bq, qb, (const T*)nullptr, flag);
    gemm_naive<T, CC, CC, 0, 0, 0, WANT><<<dim3(32, 49, Bc), 256, 0, stream>>>(xn, Wk, bk, kb, (const T*)nullptr, flag);
    gemm_naive<T, CC, CC, 0, 0, 0, WANT><<<dim3(32, 49, Bc), 256, 0, stream>>>(xn, Wv, bv, vb, (const T*)nullptr, flag);
    attn_naive<T, WANT><<<dim3(4, NHEADS, Bc), 256, 0, stream>>>(qb, kb, vb, relb, reli, attn_out, flag);
    gemm_naive<T, CC, CC, 0, 1, 0, WANT><<<dim3(32, 49, Bc), 256, 0, stream>>>(attn_out, Wo, bo, x1, xc, flag);
    gemm_naive<T, FFD, CC, 1, 0, 0, WANT><<<dim3(128, 49, Bc), 256, 0, stream>>>(x1, W1, b1, ff1, (const T*)nullptr, flag);
    gemm_naive<T, CC, FFD, 0, 2, 1, WANT><<<dim3(32, 49, Bc), 256, 0, stream>>>(ff1, W2, b2, outc, x1, flag);
  }
}

extern "C" void kernel_launch(void* const* d_in, const int* in_sizes, int n_in,
                              void* d_out, int out_size, void* d_ws, size_t ws_size,
                              hipStream_t stream)
{
  int* flag = (int*)d_ws;
  char* base = (char*)d_ws + 256;
  size_t avail = ws_size > 256 ? ws_size - 256 : 0;

  const size_t REQ_FAST = 102498304;   // fast fp32 path total footprint
  const size_t PB16 = (size_t)(4 * NN * CC + NN * FFD) * 2;  // 6,422,528
  const size_t PB32 = (size_t)(4 * NN * CC + NN * FFD) * 4;  // 12,845,056

  // Host-side dtype resolution by exact byte size of x (16x512x28x28):
  // fp32 = 25,690,112 B; bf16 = 12,845,056 B. Anything else -> device detector.
  int dt = -1;
  if (n_in > 0) {
    if (in_sizes[0] == 25690112) dt = 0;
    else if (in_sizes[0] == 12845056) dt = 1;
  }

  if (dt == 0) {
    set_flag<<<dim3(1), 1, 0, stream>>>(flag, 0);
    if (avail >= REQ_FAST) {
      run_fast_fp32(d_in, d_out, base, flag, stream);
    } else {
      int Bc32 = 1;
      for (int c : {16, 8, 4, 2}) {
        if ((size_t)c * PB32 <= avail) { Bc32 = c; break; }
      }
      run_pipeline<float, 0>(d_in, d_out, base, Bc32, flag, stream);
    }
    return;
  }
  if (dt == 1) {
    set_flag<<<dim3(1), 1, 0, stream>>>(flag, 1);
    int Bc16 = 1;
    for (int c : {16, 8, 4, 2}) {
      if ((size_t)c * PB16 <= avail) { Bc16 = c; break; }
    }
    run_pipeline<bf16, 1>(d_in, d_out, base, Bc16, flag, stream);
    return;
  }

  // Ambiguous size: old behavior (device detector + both flag-gated paths).
  detect_dtype<<<dim3(1), 256, 0, stream>>>((const unsigned int*)d_in[0], flag);
  if (avail >= REQ_FAST) {
    run_fast_fp32(d_in, d_out, base, flag, stream);
  } else {
    int Bc32 = 1;
    for (int c : {16, 8, 4, 2}) {
      if ((size_t)c * PB32 <= avail) { Bc32 = c; break; }
    }
    run_pipeline<float, 0>(d_in, d_out, base, Bc32, flag, stream);
  }
  int Bc16 = 1;
  for (int c : {16, 8, 4, 2}) {
    if ((size_t)c * PB16 <= avail) { Bc16 = c; break; }
  }
  run_pipeline<bf16, 1>(d_in, d_out, base, Bc16, flag, stream);
}

// Round 15
// 530.292 us; speedup vs baseline: 1.4037x; 1.0422x over previous
//
#include <hip/hip_runtime.h>
#include <hip/hip_bf16.h>
#include <math.h>
#include <stdint.h>

// CoAtNet transformer block, MI355X. R19 = R18 + SPLITB template flag:
// FF1 and Wo use single-bf16 weights (1 MFMA/fragment, 2/3 staging, less
// LDS -> more blocks/CU). QKV (score path) and FF2 (direct output) keep
// the 2-MFMA hi/lo split. Error budget: FF1 ~2.7e-3, Wo ~1.8e-3 on an
// output whose absmax floor is 0.03125 -- invisible.

typedef __bf16 bf16;
typedef __attribute__((ext_vector_type(8))) __bf16 bf16x8;
typedef __attribute__((ext_vector_type(4))) __bf16 bf16x4;
typedef __attribute__((ext_vector_type(4))) float f32x4;

#define NN 784      // H*W tokens
#define CC 512      // channels
#define NHEADS 16
#define DHEAD 32
#define FFD 2048
#define NBATCH 16
#define NREL 1596
#define MFULL (NBATCH * NN)   // 12544 = 98 * 128
#define PACKSZ ((size_t)6422528)  // elements per qkv-pack region

// ---------------------------------------------------------------------------
// Dtype detector (fallback only): flag=1 -> bf16, flag=0 -> fp32.
// ---------------------------------------------------------------------------
__global__ __launch_bounds__(256) void detect_dtype(const unsigned int* xw, int* flag)
{
  __shared__ int cnt[256];
  int plausible = 0;
  for (int i = threadIdx.x; i < 1024; i += 256) {
    unsigned w = xw[i];
    unsigned lo = w & 0xFFFFu;
    unsigned e = (lo >> 7) & 0xFFu;
    if (lo == 0u || (e >= 90u && e <= 140u)) plausible++;
  }
  cnt[threadIdx.x] = plausible;
  __syncthreads();
  if (threadIdx.x == 0) {
    int tot = 0;
    for (int i = 0; i < 256; i++) tot += cnt[i];
    flag[0] = (tot >= 768) ? 1 : 0;
  }
}

__global__ void set_flag(int* flag, int v) { flag[0] = v; }

// ===========================================================================
// FP32 fast path (flag == 0)
// ===========================================================================

// All six weight transposes in ONE kernel.
__global__ __launch_bounds__(256) void transpose_split_all(
    const float* __restrict__ Wq, const float* __restrict__ Wk,
    const float* __restrict__ Wv, const float* __restrict__ Wo,
    const float* __restrict__ W1, const float* __restrict__ W2,
    bf16* __restrict__ WqkvT_h, bf16* __restrict__ WqkvT_l,
    bf16* __restrict__ WoT_h,   bf16* __restrict__ WoT_l,
    bf16* __restrict__ W1T_h,   bf16* __restrict__ W1T_l,
    bf16* __restrict__ W2T_h,   bf16* __restrict__ W2T_l,
    const int* __restrict__ flag)
{
  if (flag[0] != 0) return;
  int id = blockIdx.x;
  const float* W; bf16 *th, *tl; int K, Nout, roff, nx;
  if (id < 256)       { W = Wq; th = WqkvT_h; tl = WqkvT_l; K = 512;  Nout = 512;  roff = 0;    nx = 16; }
  else if (id < 512)  { W = Wk; th = WqkvT_h; tl = WqkvT_l; K = 512;  Nout = 512;  roff = 512;  nx = 16; id -= 256; }
  else if (id < 768)  { W = Wv; th = WqkvT_h; tl = WqkvT_l; K = 512;  Nout = 512;  roff = 1024; nx = 16; id -= 512; }
  else if (id < 1024) { W = Wo; th = WoT_h;   tl = WoT_l;   K = 512;  Nout = 512;  roff = 0;    nx = 16; id -= 768; }
  else if (id < 2048) { W = W1; th = W1T_h;   tl = W1T_l;   K = 512;  Nout = 2048; roff = 0;    nx = 64; id -= 1024; }
  else                { W = W2; th = W2T_h;   tl = W2T_l;   K = 2048; Nout = 512;  roff = 0;    nx = 16; id -= 2048; }
  const int n0 = (id % nx) * 32, k0 = (id / nx) * 32;

  __shared__ float tile[32][33];
  int tx = threadIdx.x & 31, ty = threadIdx.x >> 5;   // 32 x 8
  #pragma unroll
  for (int r = 0; r < 32; r += 8)
    tile[ty + r][tx] = W[(size_t)(k0 + ty + r) * Nout + n0 + tx];
  __syncthreads();
  #pragma unroll
  for (int r = 0; r < 32; r += 8) {
    float v = tile[tx][ty + r];            // = W[k0+tx][n0+ty+r]
    bf16 h = (bf16)v;
    float lo = v - (float)h;
    size_t idx = (size_t)(roff + n0 + ty + r) * K + k0 + tx;
    th[idx] = h;
    tl[idx] = (bf16)lo;
  }
}

// Coalesced LayerNorm: x (b,C,N) fp32 -> xn single bf16 (M,C).
__global__ __launch_bounds__(256) void ln_coal(
    const float* __restrict__ x, const float* __restrict__ lnw,
    const float* __restrict__ lnb, bf16* __restrict__ xh,
    const int* __restrict__ flag)
{
  if (flag[0] != 0) return;
  const int b = blockIdx.y;
  const int n0 = blockIdx.x * 64;
  const int w = threadIdx.x >> 6, l = threadIdx.x & 63;
  const bool act = (n0 + l) < NN;
  int tok = n0 + l; if (tok >= NN) tok = NN - 1;
  const float* xb = x + ((size_t)b * CC + w * 128) * NN + tok;
  float vals[128];
  float s = 0.f, ss = 0.f;
  #pragma unroll
  for (int c = 0; c < 128; c++) {
    float v = xb[(size_t)c * NN];
    vals[c] = v; s += v; ss += v * v;
  }
  __shared__ float S[4][64], SS[4][64];
  S[w][l] = s; SS[w][l] = ss;
  __syncthreads();
  const float St  = S[0][l] + S[1][l] + S[2][l] + S[3][l];
  const float SSt = SS[0][l] + SS[1][l] + SS[2][l] + SS[3][l];
  const float mu  = St * (1.f / 512.f);
  const float var = SSt * (1.f / 512.f) - mu * mu;
  const float rstd = rsqrtf(var + 1e-5f);
  if (act) {
    const size_t row = ((size_t)b * NN + n0 + l) * CC + w * 128;
    #pragma unroll
    for (int cc = 0; cc < 16; cc++) {
      bf16x8 o;
      #pragma unroll
      for (int e = 0; e < 8; e++) {
        const int c = cc * 8 + e;
        o[e] = (bf16)((vals[c] - mu) * rstd * lnw[w * 128 + c] + lnb[w * 128 + c]);
      }
      *(bf16x8*)(xh + row + cc * 8) = o;
    }
  }
}

// ---------------------------------------------------------------------------
// Split GEMM (R11/R15 structure; BN + SPLITB templated): 128xBN tile, 4 waves
// 2x2 (wave tile 64 x BN/2), dbuf 1-barrier K-loop (BK=32).
// SPLITB=1: C = A*Bh + A*Bl (2 MFMA). SPLITB=0: C = A*Bh (1 MFMA, no sBl).
// 1D XCD chunk swizzle. ACT: 1 = exact gelu.
// RESM: 0 none; 1 += extra_f[(b,C,N)] fp32; 2 += ex_hi+ex_lo [(M,CC)] split.
// OUTM: 3 split hi/lo (M,NOUT); 4 fp32 (b,C,N); 6 single bf16 (M,NOUT);
//       5 QKV pack single: Q @0, K @PACKSZ, Vt [bh][32][784] @2*PACKSZ.
// ---------------------------------------------------------------------------
template <int NOUT, int KD, int ACT, int RESM, int OUTM, int BN = 128, int SPLITB = 1>
__global__ __launch_bounds__(256) void gemm2(
    const bf16* __restrict__ A,
    const bf16* __restrict__ Bh, const bf16* __restrict__ Bl,
    const float* __restrict__ bias_q, const float* __restrict__ bias_k,
    const float* __restrict__ bias_v,
    float* __restrict__ outf, bf16* __restrict__ out_hi, bf16* __restrict__ out_lo,
    const float* __restrict__ extra_f, const bf16* __restrict__ ex_hi,
    const bf16* __restrict__ ex_lo,
    int M, const int* __restrict__ flag)
{
  if (flag[0] != 0) return;
  constexpr int NFR = BN / 32;      // B fragments per wave (n dir)
  constexpr int WN  = BN / 2;       // wave tile n-width
  constexpr int BSTG = BN / 64;     // B staging loads per thread per tile
  __shared__ bf16 sA [2][128 * 32];
  __shared__ bf16 sBh[2][BN * 32];
  __shared__ bf16 sBl[SPLITB ? 2 : 1][SPLITB ? BN * 32 : 1];
  const int t = threadIdx.x;
  const int lane = t & 63;
  const int w = t >> 6;
  const int wr = w >> 1, wc = w & 1;
  const int lr = lane & 15, kg = lane >> 4;

  // 1D XCD-chunked bijective swizzle (all grids here have nwg % 8 == 0).
  int wg = blockIdx.y * gridDim.x + blockIdx.x;
  const int nwg = gridDim.x * gridDim.y;
  if ((nwg & 7) == 0) {
    const int cpx = nwg >> 3;
    wg = (wg & 7) * cpx + (wg >> 3);
  }
  const int tile_n = (wg % gridDim.x) * BN;
  const int tile_m = (wg / gridDim.x) * 128;

  f32x4 acc[4][NFR];
  #pragma unroll
  for (int m = 0; m < 4; m++)
    #pragma unroll
    for (int n = 0; n < NFR; n++) acc[m][n] = (f32x4)0.f;

  // A staging: 512 x 16B segs (2/thread). B staging: BN*4 segs (BSTG/thread).
  size_t aoff[2];
  #pragma unroll
  for (int i = 0; i < 2; i++) {
    const int seg = t + 256 * i;
    int r = tile_m + (seg >> 2); if (r >= M) r = M - 1;
    aoff[i] = (size_t)r * KD + (seg & 3) * 8;
  }
  size_t bsoff[BSTG > 0 ? BSTG : 1];
  #pragma unroll
  for (int i = 0; i < BSTG; i++) {
    const int seg = t + 256 * i;
    bsoff[i] = (size_t)(tile_n + (seg >> 2)) * KD + (seg & 3) * 8;
  }

  #define STAGE(BUF, KO)                                                        \
    do {                                                                        \
      _Pragma("unroll")                                                         \
      for (int i = 0; i < 2; i++)                                               \
        __builtin_amdgcn_global_load_lds(                                       \
            (const __attribute__((address_space(1))) void*)(A + aoff[i] + (KO)),\
            (__attribute__((address_space(3))) void*)(sA[BUF] + (t + 256 * i) * 8), 16, 0, 0); \
      _Pragma("unroll")                                                         \
      for (int i = 0; i < BSTG; i++) {                                          \
        __builtin_amdgcn_global_load_lds(                                       \
            (const __attribute__((address_space(1))) void*)(Bh + bsoff[i] + (KO)),\
            (__attribute__((address_space(3))) void*)(sBh[BUF] + (t + 256 * i) * 8), 16, 0, 0); \
        if (SPLITB)                                                             \
          __builtin_amdgcn_global_load_lds(                                     \
              (const __attribute__((address_space(1))) void*)(Bl + bsoff[i] + (KO)),\
              (__attribute__((address_space(3))) void*)(sBl[BUF] + (t + 256 * i) * 8), 16, 0, 0); \
      }                                                                         \
    } while (0)

  // Prologue: stage first tile, drain, barrier.
  STAGE(0, 0);
  asm volatile("s_waitcnt vmcnt(0)" ::: "memory");
  __builtin_amdgcn_sched_barrier(0);
  __builtin_amdgcn_s_barrier();
  __builtin_amdgcn_sched_barrier(0);

  int cur = 0;
  for (int k0 = 0; k0 < KD; k0 += 32) {
    if (k0 + 32 < KD) {
      if (cur) STAGE(0, k0 + 32); else STAGE(1, k0 + 32);
    }
    const bf16* pA  = sA [cur];
    const bf16* pBh = sBh[cur];
    const bf16* pBl = SPLITB ? sBl[cur] : sBh[cur];
    bf16x8 af[4], bhf[NFR], blf[NFR];
    #pragma unroll
    for (int m = 0; m < 4; m++) {
      const int off = (wr * 64 + m * 16 + lr) * 32 + kg * 8;
      af[m] = *(const bf16x8*)(pA + off);
    }
    #pragma unroll
    for (int n = 0; n < NFR; n++) {
      const int off = (wc * WN + n * 16 + lr) * 32 + kg * 8;
      bhf[n] = *(const bf16x8*)(pBh + off);
      if (SPLITB) blf[n] = *(const bf16x8*)(pBl + off);
    }
    #pragma unroll
    for (int m = 0; m < 4; m++)
      #pragma unroll
      for (int n = 0; n < NFR; n++) {
        acc[m][n] = __builtin_amdgcn_mfma_f32_16x16x32_bf16(af[m], bhf[n], acc[m][n], 0, 0, 0);
        if (SPLITB)
          acc[m][n] = __builtin_amdgcn_mfma_f32_16x16x32_bf16(af[m], blf[n], acc[m][n], 0, 0, 0);
      }
    asm volatile("s_waitcnt vmcnt(0)" ::: "memory");
    __builtin_amdgcn_sched_barrier(0);
    __builtin_amdgcn_s_barrier();
    __builtin_amdgcn_sched_barrier(0);
    cur ^= 1;
  }
  #undef STAGE

  // Epilogue. C/D layout: col = lane&15, row = 4*(lane>>4) + reg.
  #pragma unroll
  for (int m = 0; m < 4; m++) {
    const int r0 = tile_m + wr * 64 + m * 16 + kg * 4;
    #pragma unroll
    for (int n = 0; n < NFR; n++) {
      const int cg = tile_n + wc * WN + n * 16 + lr;
      float bv;
      if (OUTM == 5) {
        const int reg2 = cg >> 9;
        const float* bp = reg2 == 0 ? bias_q : (reg2 == 1 ? bias_k : bias_v);
        bv = bp[cg & 511];
      } else {
        bv = bias_q[cg];
      }
      #pragma unroll
      for (int j = 0; j < 4; j++) {
        const int rg = r0 + j;
        if (rg >= M) continue;
        float vacc = acc[m][n][j] + bv;
        if (ACT == 1) vacc = 0.5f * vacc * (1.f + erff(vacc * 0.70710678118654752f));
        if (RESM == 1) {
          int bl_ = rg / NN, nn = rg - bl_ * NN;
          vacc += extra_f[((size_t)bl_ * CC + cg) * NN + nn];
        }
        if (RESM == 2) {
          size_t ei = (size_t)rg * CC + cg;
          vacc += (float)ex_hi[ei] + (float)ex_lo[ei];
        }
        if (OUTM == 3) {
          size_t oi = (size_t)rg * NOUT + cg;
          bf16 h = (bf16)vacc;
          out_hi[oi] = h;
          out_lo[oi] = (bf16)(vacc - (float)h);
        } else if (OUTM == 4) {
          int bl_ = rg / NN, nn = rg - bl_ * NN;
          outf[((size_t)bl_ * CC + cg) * NN + nn] = vacc;
        } else if (OUTM == 6) {
          out_hi[(size_t)rg * NOUT + cg] = (bf16)vacc;
        } else if (OUTM == 5) {
          const int reg2 = cg >> 9;
          const int c = cg & 511;
          const int hh = c >> 5, dd = c & 31;
          const int bl_ = rg / NN, nn = rg - bl_ * NN;
          const int bh_ = bl_ * NHEADS + hh;
          bf16 h = (bf16)vacc;
          if (reg2 == 0) {
            out_hi[((size_t)bh_ * NN + nn) * 32 + dd] = h;
          } else if (reg2 == 1) {
            out_hi[PACKSZ + ((size_t)bh_ * NN + nn) * 32 + dd] = h;
          } else {
            out_hi[2 * PACKSZ + ((size_t)bh_ * 32 + dd) * NN + nn] = h;
          }
        }
      }
    }
  }
}

// ---------------------------------------------------------------------------
// MFMA flash attention (unchanged). Grid (13, H, B), 4 waves/block.
// ---------------------------------------------------------------------------
__global__ __launch_bounds__(256) void attn_mfma(
    const bf16* __restrict__ pack, const float* __restrict__ relb,
    bf16* __restrict__ o_out, const int* __restrict__ flag)
{
  if (flag[0] != 0) return;
  const int h = blockIdx.y, b = blockIdx.z;
  __shared__ float biasLds[NREL];
  for (int i = threadIdx.x; i < NREL; i += 256) biasLds[i] = relb[(size_t)h * NREL + i];
  __syncthreads();
  const int w = threadIdx.x >> 6, lane = threadIdx.x & 63;
  const int qtile = blockIdx.x * 4 + w;
  if (qtile >= 49) return;
  const int kg = lane >> 4, lq = lane & 15;
  const int qg = qtile * 16 + lq;
  const int bh = b * NHEADS + h;
  const bf16* Q  = pack;
  const bf16* K  = pack + PACKSZ;
  const bf16* Vt = pack + 2 * PACKSZ;
  __shared__ bf16 Plds[4][16][72];

  const bf16x8 qf = *(const bf16x8*)(Q + ((size_t)bh * NN + qg) * 32 + kg * 8);

  float m = -1e30f, l = 0.f;
  f32x4 o0 = (f32x4)0.f, o1 = (f32x4)0.f;
  const float* bb = biasLds + 812 - qg;   // bb[kv] = bias(kv, q=qg)
  const size_t vrow0 = ((size_t)bh * 32 + lq) * NN;
  const size_t vrow1 = ((size_t)bh * 32 + 16 + lq) * NN;

  for (int c = 0; c < 12; c++) {
    const int c0 = c * 64;
    f32x4 st[4];
    #pragma unroll
    for (int t = 0; t < 4; t++) {
      const int kvr = c0 + t * 16 + lq;
      const bf16x8 kf = *(const bf16x8*)(K + ((size_t)bh * NN + kvr) * 32 + kg * 8);
      st[t] = __builtin_amdgcn_mfma_f32_16x16x32_bf16(kf, qf, (f32x4)0.f, 0, 0, 0);
    }
    float cm = -1e30f;
    #pragma unroll
    for (int t = 0; t < 4; t++)
      #pragma unroll
      for (int r = 0; r < 4; r++) {
        st[t][r] += bb[c0 + t * 16 + 4 * kg + r];
        cm = fmaxf(cm, st[t][r]);
      }
    cm = fmaxf(cm, __shfl_xor(cm, 16));
    cm = fmaxf(cm, __shfl_xor(cm, 32));
    const float mn = fmaxf(m, cm);
    const float al = __expf(m - mn);
    m = mn;
    float cl = 0.f;
    #pragma unroll
    for (int t = 0; t < 4; t++) {
      bf16x4 pk;
      #pragma unroll
      for (int r = 0; r < 4; r++) {
        float p = __expf(st[t][r] - m);
        bf16 pb = (bf16)p;
        pk[r] = pb;
        cl += (float)pb;
      }
      *(bf16x4*)(&Plds[w][lq][t * 16 + 4 * kg]) = pk;
    }
    cl += __shfl_xor(cl, 16);
    cl += __shfl_xor(cl, 32);
    l = l * al + cl;
    #pragma unroll
    for (int r = 0; r < 4; r++) {
      const float ar = __shfl(al, (lane & 48) | (kg * 4 + r));
      o0[r] *= ar; o1[r] *= ar;
    }
    #pragma unroll
    for (int s2 = 0; s2 < 2; s2++) {
      const bf16x8 pa = *(const bf16x8*)(&Plds[w][lq][s2 * 32 + kg * 8]);
      const bf16x8 v0 = *(const bf16x8*)(Vt + vrow0 + c0 + s2 * 32 + kg * 8);
      const bf16x8 v1 = *(const bf16x8*)(Vt + vrow1 + c0 + s2 * 32 + kg * 8);
      o0 = __builtin_amdgcn_mfma_f32_16x16x32_bf16(pa, v0, o0, 0, 0, 0);
      o1 = __builtin_amdgcn_mfma_f32_16x16x32_bf16(pa, v1, o1, 0, 0, 0);
    }
  }

  // Tail: kv 768..783.
  {
    const int c0 = 768;
    const int kvr = c0 + lq;
    const bf16x8 kf = *(const bf16x8*)(K + ((size_t)bh * NN + kvr) * 32 + kg * 8);
    f32x4 a = __builtin_amdgcn_mfma_f32_16x16x32_bf16(kf, qf, (f32x4)0.f, 0, 0, 0);
    float cm = -1e30f;
    #pragma unroll
    for (int r = 0; r < 4; r++) {
      a[r] += bb[c0 + 4 * kg + r];
      cm = fmaxf(cm, a[r]);
    }
    cm = fmaxf(cm, __shfl_xor(cm, 16));
    cm = fmaxf(cm, __shfl_xor(cm, 32));
    const float mn = fmaxf(m, cm);
    const float al = __expf(m - mn);
    m = mn;
    float cl = 0.f;
    bf16x4 pk, zk;
    #pragma unroll
    for (int r = 0; r < 4; r++) {
      float p = __expf(a[r] - m);
      bf16 pb = (bf16)p;
      pk[r] = pb;
      zk[r] = (bf16)0.f;
      cl += (float)pb;
    }
    *(bf16x4*)(&Plds[w][lq][4 * kg]) = pk;
    *(bf16x4*)(&Plds[w][lq][16 + 4 * kg]) = zk;   // zero-pad k 16..31
    cl += __shfl_xor(cl, 16);
    cl += __shfl_xor(cl, 32);
    l = l * al + cl;
    #pragma unroll
    for (int r = 0; r < 4; r++) {
      const float ar = __shfl(al, (lane & 48) | (kg * 4 + r));
      o0[r] *= ar; o1[r] *= ar;
    }
    bf16x8 vz;
    #pragma unroll
    for (int e = 0; e < 8; e++) vz[e] = (bf16)0.f;
    const int voff = c0 + (kg < 2 ? kg * 8 : 0);
    bf16x8 v0 = *(const bf16x8*)(Vt + vrow0 + voff);
    bf16x8 v1 = *(const bf16x8*)(Vt + vrow1 + voff);
    if (kg >= 2) { v0 = vz; v1 = vz; }
    const bf16x8 pa = *(const bf16x8*)(&Plds[w][lq][kg * 8]);
    o0 = __builtin_amdgcn_mfma_f32_16x16x32_bf16(pa, v0, o0, 0, 0, 0);
    o1 = __builtin_amdgcn_mfma_f32_16x16x32_bf16(pa, v1, o1, 0, 0, 0);
  }

  const float inv = 1.f / l;
  #pragma unroll
  for (int r = 0; r < 4; r++) {
    const float ir = __shfl(inv, (lane & 48) | (kg * 4 + r));
    const int rq = qtile * 16 + kg * 4 + r;
    const size_t oi = ((size_t)b * NN + rq) * CC + h * DHEAD;
    o_out[oi + lq]      = (bf16)(o0[r] * ir);
    o_out[oi + 16 + lq] = (bf16)(o1[r] * ir);
  }
}

// ---------------------------------------------------------------------------
// fp32 fast pipeline (full batch)
// ---------------------------------------------------------------------------
static void run_fast_fp32(void* const* d_in, void* d_out, char* base,
                          const int* flag, hipStream_t stream)
{
  const float* x    = (const float*)d_in[0];
  const float* lnw  = (const float*)d_in[1];
  const float* lnb  = (const float*)d_in[2];
  const float* Wq   = (const float*)d_in[3];
  const float* bq   = (const float*)d_in[4];
  const float* Wk   = (const float*)d_in[5];
  const float* bk   = (const float*)d_in[6];
  const float* Wv   = (const float*)d_in[7];
  const float* bv   = (const float*)d_in[8];
  const float* Wo   = (const float*)d_in[9];
  const float* bo   = (const float*)d_in[10];
  const float* relb = (const float*)d_in[11];
  const float* W1   = (const float*)d_in[12];
  const float* b1   = (const float*)d_in[13];
  const float* W2   = (const float*)d_in[14];
  const float* b2   = (const float*)d_in[15];
  float* outp = (float*)d_out;

  bf16* WqkvT_h = (bf16*)(base);
  bf16* WqkvT_l = WqkvT_h + (size_t)1536 * 512;
  bf16* WoT_h   = WqkvT_l + (size_t)1536 * 512;
  bf16* WoT_l   = WoT_h   + (size_t)512 * 512;
  bf16* W1T_h   = WoT_l   + (size_t)512 * 512;
  bf16* W1T_l   = W1T_h   + (size_t)2048 * 512;
  bf16* W2T_h   = W1T_l   + (size_t)2048 * 512;
  bf16* W2T_l   = W2T_h   + (size_t)512 * 2048;
  bf16* xn   = (bf16*)(base + 12582912);
  bf16* qkvp = (bf16*)(base + 25427968);
  bf16* x1_h = (bf16*)(base + 25427968);
  bf16* x1_l = (bf16*)(base + 38273024);
  bf16* ff   = (bf16*)(base + 51118080);
  bf16* at   = xn;   // xn dead after QKV

  transpose_split_all<<<dim3(3072), 256, 0, stream>>>(
      Wq, Wk, Wv, Wo, W1, W2,
      WqkvT_h, WqkvT_l, WoT_h, WoT_l, W1T_h, W1T_l, W2T_h, W2T_l, flag);

  const int M = MFULL;            // 12544 = 98 * 128
  const int gm = M / 128;         // 98

  ln_coal<<<dim3(13, NBATCH), 256, 0, stream>>>(x, lnw, lnb, xn, flag);

  // QKV fused -> single-bf16 attention pack. (BN=128, split B: score path)
  gemm2<1536, 512, 0, 0, 5, 128, 1><<<dim3(12, gm), 256, 0, stream>>>(
      xn, WqkvT_h, WqkvT_l, bq, bk, bv,
      (float*)nullptr, qkvp, (bf16*)nullptr,
      (const float*)nullptr, (const bf16*)nullptr, (const bf16*)nullptr,
      M, flag);

  attn_mfma<<<dim3(13, NHEADS, NBATCH), 256, 0, stream>>>(qkvp, relb, at, flag);

  // Wo: + residual x (b,C,N), out split x1. BN=64, SINGLE B (err ~1.8e-3).
  gemm2<512, 512, 0, 1, 3, 64, 0><<<dim3(8, gm), 256, 0, stream>>>(
      at, WoT_h, WoT_l, bo, (const float*)nullptr, (const float*)nullptr,
      (float*)nullptr, x1_h, x1_l,
      x, (const bf16*)nullptr, (const bf16*)nullptr,
      M, flag);

  // FF1: gelu, out single bf16. BN=128, SINGLE B (err ~2.7e-3 via FF2).
  gemm2<2048, 512, 1, 0, 6, 128, 0><<<dim3(16, gm), 256, 0, stream>>>(
      x1_h, W1T_h, W1T_l, b1, (const float*)nullptr, (const float*)nullptr,
      (float*)nullptr, ff, (bf16*)nullptr,
      (const float*)nullptr, (const bf16*)nullptr, (const bf16*)nullptr,
      M, flag);

  // FF2: + residual x1 (split), out fp32 (b,C,N). BN=64, split B (output path).
  gemm2<512, 2048, 0, 2, 4, 64, 1><<<dim3(8, gm), 256, 0, stream>>>(
      ff, W2T_h, W2T_l, b2, (const float*)nullptr, (const float*)nullptr,
      outp, (bf16*)nullptr, (bf16*)nullptr,
      (const float*)nullptr, x1_h, x1_l,
      M, flag);
}

// ===========================================================================
// Naive kernels (fallback paths)
// ===========================================================================
template <typename T, int WANT>
__global__ __launch_bounds__(256) void ln_naive(
    const T* __restrict__ x, const T* __restrict__ lnw, const T* __restrict__ lnb,
    T* __restrict__ xn, const int* __restrict__ flag)
{
  if (flag[0] != WANT) return;
  int bn = blockIdx.x;
  int b = bn / NN, n = bn - b * NN;
  const T* xb = x + (size_t)b * CC * NN + n;
  int t = threadIdx.x;
  float v0 = (float)xb[(size_t)t * NN];
  float v1 = (float)xb[(size_t)(t + 256) * NN];
  float s = v0 + v1, ss = v0 * v0 + v1 * v1;
  #pragma unroll
  for (int m = 32; m >= 1; m >>= 1) {
    s  += __shfl_xor(s,  m);
    ss += __shfl_xor(ss, m);
  }
  __shared__ float red[2][4];
  int w = t >> 6, l = t & 63;
  if (l == 0) { red[0][w] = s; red[1][w] = ss; }
  __syncthreads();
  float S  = red[0][0] + red[0][1] + red[0][2] + red[0][3];
  float SS = red[1][0] + red[1][1] + red[1][2] + red[1][3];
  float mu  = S * (1.f / 512.f);
  float var = SS * (1.f / 512.f) - mu * mu;
  float rstd = rsqrtf(var + 1e-5f);
  T* o = xn + (size_t)bn * CC;
  o[t]       = (T)(((v0 - mu) * rstd) * (float)lnw[t]       + (float)lnb[t]);
  o[t + 256] = (T)(((v1 - mu) * rstd) * (float)lnw[t + 256] + (float)lnb[t + 256]);
}

template <typename T, int NOUT, int KD, int ACT, int RESM, int OUTM, int WANT>
__global__ __launch_bounds__(256) void gemm_naive(
    const T* __restrict__ A, const T* __restrict__ W, const T* __restrict__ bias,
    T* __restrict__ out, const T* __restrict__ extra, const int* __restrict__ flag)
{
  if (flag[0] != WANT) return;
  __shared__ float a_t[16][17];
  __shared__ float w_t[16][17];
  int tx = threadIdx.x & 15, ty = threadIdx.x >> 4;
  int m0 = blockIdx.y * 16, bz = blockIdx.z;
  int mg = m0 + ty;
  int jg = blockIdx.x * 16 + tx;
  int ar = mg < NN ? mg : NN - 1;
  const T* Ab = A + (size_t)bz * NN * KD;
  float acc = 0.f;
  for (int k0 = 0; k0 < KD; k0 += 16) {
    a_t[ty][tx] = (float)Ab[(size_t)ar * KD + k0 + tx];
    w_t[ty][tx] = (float)W[(size_t)(k0 + ty) * NOUT + jg];
    __syncthreads();
    #pragma unroll
    for (int kk = 0; kk < 16; kk++)
      acc += a_t[ty][kk] * w_t[kk][tx];
    __syncthreads();
  }
  if (mg >= NN) return;
  acc += (float)bias[jg];
  if (ACT == 1) acc = 0.5f * acc * (1.f + erff(acc * 0.70710678118654752f));
  if (RESM == 1) acc += (float)extra[((size_t)bz * CC + jg) * NN + mg];
  if (RESM == 2) acc += (float)extra[((size_t)bz * NN + mg) * CC + jg];
  if (OUTM == 0) out[((size_t)bz * NN + mg) * NOUT + jg] = (T)acc;
  else           out[((size_t)bz * NOUT + jg) * NN + mg] = (T)acc;
}

template <typename T, int WANT>
__global__ __launch_bounds__(256) void attn_naive(
    const T* __restrict__ q, const T* __restrict__ k, const T* __restrict__ v,
    const T* __restrict__ rel_bias, const int* __restrict__ rel_idx,
    T* __restrict__ attn_out, const int* __restrict__ flag)
{
  if (flag[0] != WANT) return;
  int i = blockIdx.x * 256 + threadIdx.x;
  int h = blockIdx.y, b = blockIdx.z;
  if (i >= NN) return;
  const T* qr = q + ((size_t)b * NN + i) * CC + h * DHEAD;
  float qv[DHEAD];
  #pragma unroll
  for (int d = 0; d < DHEAD; d++) qv[d] = (float)qr[d];
  const int* ridx = rel_idx + (size_t)i * NN;
  const T* rb = rel_bias + (size_t)h * NREL;
  const T* kb = k + (size_t)b * NN * CC + h * DHEAD;
  const T* vb = v + (size_t)b * NN * CC + h * DHEAD;

  float m = -1e30f;
  for (int j = 0; j < NN; j++) {
    const T* kr = kb + (size_t)j * CC;
    float s = 0.f;
    #pragma unroll
    for (int d = 0; d < DHEAD; d++) s += qv[d] * (float)kr[d];
    s += (float)rb[ridx[j]];
    m = fmaxf(m, s);
  }
  float l = 0.f;
  float o[DHEAD];
  #pragma unroll
  for (int d = 0; d < DHEAD; d++) o[d] = 0.f;
  for (int j = 0; j < NN; j++) {
    const T* kr = kb + (size_t)j * CC;
    float s = 0.f;
    #pragma unroll
    for (int d = 0; d < DHEAD; d++) s += qv[d] * (float)kr[d];
    s += (float)rb[ridx[j]];
    float p = __expf(s - m);
    l += p;
    const T* vr = vb + (size_t)j * CC;
    #pragma unroll
    for (int d = 0; d < DHEAD; d++) o[d] += p * (float)vr[d];
  }
  float inv = 1.f / l;
  T* op = attn_out + ((size_t)b * NN + i) * CC + h * DHEAD;
  #pragma unroll
  for (int d = 0; d < DHEAD; d++) op[d] = (T)(o[d] * inv);
}

template <typename T, int WANT>
static void run_pipeline(void* const* d_in, void* d_out, char* buf, int Bc,
                         const int* flag, hipStream_t stream)
{
  const T* x    = (const T*)d_in[0];
  const T* lnw  = (const T*)d_in[1];
  const T* lnb  = (const T*)d_in[2];
  const T* Wq   = (const T*)d_in[3];
  const T* bq   = (const T*)d_in[4];
  const T* Wk   = (const T*)d_in[5];
  const T* bk   = (const T*)d_in[6];
  const T* Wv   = (const T*)d_in[7];
  const T* bv   = (const T*)d_in[8];
  const T* Wo   = (const T*)d_in[9];
  const T* bo   = (const T*)d_in[10];
  const T* relb = (const T*)d_in[11];
  const T* W1   = (const T*)d_in[12];
  const T* b1   = (const T*)d_in[13];
  const T* W2   = (const T*)d_in[14];
  const T* b2   = (const T*)d_in[15];
  const int* reli = (const int*)d_in[16];
  T* outp = (T*)d_out;

  const size_t TOK = (size_t)NN * CC;
  T* xn  = (T*)(buf);
  T* qb  = (T*)(buf + (size_t)Bc * TOK * 4);
  T* kb  = (T*)(buf + 2 * (size_t)Bc * TOK * 4);
  T* vb  = (T*)(buf + 3 * (size_t)Bc * TOK * 4);
  T* ff1 = (T*)(buf + 4 * (size_t)Bc * TOK * 4);
  T* attn_out = xn;
  T* x1 = qb;

  for (int c0 = 0; c0 < NBATCH; c0 += Bc) {
    const T* xc   = x    + (size_t)c0 * CC * NN;
    T*       outc = outp + (size_t)c0 * CC * NN;
    ln_naive<T, WANT><<<dim3(Bc * NN), 256, 0, stream>>>(xc, lnw, lnb, xn, flag);
    gemm_naive<T, CC, CC, 0, 0, 0, WANT><<<dim3(32, 49, Bc), 256, 0, stream>>>(xn, Wq, bq, qb, (const T*)nullptr, flag);
    gemm_naive<T, CC, CC, 0, 0, 0, WANT><<<dim3(32, 49, Bc), 256, 0, stream>>>(xn, Wk, bk, kb, (const T*)nullptr, flag);
    gemm_naive<T, CC, CC, 0, 0, 0, WANT><<<dim3(32, 49, Bc), 256, 0, stream>>>(xn, Wv, bv, vb, (const T*)nullptr, flag);
    attn_naive<T, WANT><<<dim3(4, NHEADS, Bc), 256, 0, stream>>>(qb, kb, vb, relb, reli, attn_out, flag);
    gemm_naive<T, CC, CC, 0, 1, 0, WANT><<<dim3(32, 49, Bc), 256, 0, stream>>>(attn_out, Wo, bo, x1, xc, flag);
    gemm_naive<T, FFD, CC, 1, 0, 0, WANT><<<dim3(128, 49, Bc), 256, 0, stream>>>(x1, W1, b1, ff1, (const T*)nullptr, flag);
    gemm_naive<T, CC, FFD, 0, 2, 1, WANT><<<dim3(32, 49, Bc), 256, 0, stream>>>(ff1, W2, b2, outc, x1, flag);
  }
}

extern "C" void kernel_launch(void* const* d_in, const int* in_sizes, int n_in,
                              void* d_out, int out_size, void* d_ws, size_t ws_size,
                              hipStream_t stream)
{
  int* flag = (int*)d_ws;
  char* base = (char*)d_ws + 256;
  size_t avail = ws_size > 256 ? ws_size - 256 : 0;

  const size_t REQ_FAST = 102498304;   // fast fp32 path total footprint
  const size_t PB16 = (size_t)(4 * NN * CC + NN * FFD) * 2;  // 6,422,528
  const size_t PB32 = (size_t)(4 * NN * CC + NN * FFD) * 4;  // 12,845,056

  // Host-side dtype resolution by exact byte size of x (16x512x28x28):
  // fp32 = 25,690,112 B; bf16 = 12,845,056 B. Anything else -> device detector.
  int dt = -1;
  if (n_in > 0) {
    if (in_sizes[0] == 25690112) dt = 0;
    else if (in_sizes[0] == 12845056) dt = 1;
  }

  if (dt == 0) {
    set_flag<<<dim3(1), 1, 0, stream>>>(flag, 0);
    if (avail >= REQ_FAST) {
      run_fast_fp32(d_in, d_out, base, flag, stream);
    } else {
      int Bc32 = 1;
      for (int c : {16, 8, 4, 2}) {
        if ((size_t)c * PB32 <= avail) { Bc32 = c; break; }
      }
      run_pipeline<float, 0>(d_in, d_out, base, Bc32, flag, stream);
    }
    return;
  }
  if (dt == 1) {
    set_flag<<<dim3(1), 1, 0, stream>>>(flag, 1);
    int Bc16 = 1;
    for (int c : {16, 8, 4, 2}) {
      if ((size_t)c * PB16 <= avail) { Bc16 = c; break; }
    }
    run_pipeline<bf16, 1>(d_in, d_out, base, Bc16, flag, stream);
    return;
  }

  // Ambiguous size: old behavior (device detector + both flag-gated paths).
  detect_dtype<<<dim3(1), 256, 0, stream>>>((const unsigned int*)d_in[0], flag);
  if (avail >= REQ_FAST) {
    run_fast_fp32(d_in, d_out, base, flag, stream);
  } else {
    int Bc32 = 1;
    for (int c : {16, 8, 4, 2}) {
      if ((size_t)c * PB32 <= avail) { Bc32 = c; break; }
    }
    run_pipeline<float, 0>(d_in, d_out, base, Bc32, flag, stream);
  }
  int Bc16 = 1;
  for (int c : {16, 8, 4, 2}) {
    if ((size_t)c * PB16 <= avail) { Bc16 = c; break; }
  }
  run_pipeline<bf16, 1>(d_in, d_out, base, Bc16, flag, stream);
}